// Round 13
// baseline (637.405 us; speedup 1.0000x reference)
//
#include <hip/hip_runtime.h>
#include <math.h>

#define NN 50000
#define EE 800000
#define NEG 0.2f
#define NG (NN / 16)   // 3125 node groups

using f32x4  = __attribute__((ext_vector_type(4))) float;
using bf16x8 = __attribute__((ext_vector_type(8))) short;

__device__ __forceinline__ float lrelu(float x){ return x > 0.f ? x : NEG*x; }

__device__ __forceinline__ unsigned short f2b(float f){
    unsigned int u = __float_as_uint(f);
    return (unsigned short)((u + 0x7FFFu + ((u >> 16) & 1u)) >> 16);  // RNE
}
__device__ __forceinline__ float b2f(unsigned short h){
    return __uint_as_float(((unsigned int)h) << 16);
}

// ---------------------------------------------------------------------------
// Weight packers (fragment-order bf16).
// Fusion: chunk = ct*4 + r. k < K-1 only (ones-row handled via acc init).
// ---------------------------------------------------------------------------
__global__ void pack_w_fusion(const float* __restrict__ W, unsigned short* __restrict__ out,
                              int K, int NKC)
{
    int u = blockIdx.x * blockDim.x + threadIdx.x;
    if (u >= NKC * 16 * 64) return;
    int l = u & 63, chunk = (u >> 6) & 15, kc = u >> 10;
    int ct = chunk >> 2, r = chunk & 3;
    int c = ct * 16 + (l & 15);
    int kb = kc * 32 + (l >> 4) * 8;
    bf16x8 v;
#pragma unroll
    for (int j = 0; j < 8; ++j)
        v[j] = (short)f2b(W[((size_t)r * K + kb + j) * 64 + c]);
    *(bf16x8*)(out + (size_t)u * 8) = v;
}

// GEMM weights: chunk = ct (C/16 chunks per kc); K multiple of 32.
// PERM=1: A rows are stored head-minor (k_store = d*4+h <-> k_orig = h*64+d).
template<int PERM>
__global__ void pack_w_gemm(const float* __restrict__ W, unsigned short* __restrict__ out,
                            int K, int C)
{
    int NCH = C / 16;
    int total = (K / 32) * NCH * 64;
    int u = blockIdx.x * blockDim.x + threadIdx.x;
    if (u >= total) return;
    int l = u & 63, ch = (u >> 6) % NCH, kc = u / (64 * NCH);
    int c = ch * 16 + (l & 15);
    int kb = kc * 32 + (l >> 4) * 8;
    bf16x8 v;
#pragma unroll
    for (int j = 0; j < 8; ++j) {
        int k = kb + j;
        int ko = PERM ? ((k & 3) * 64 + (k >> 2)) : k;
        v[j] = (short)f2b(W[(size_t)ko * C + c]);
    }
    *(bf16x8*)(out + (size_t)u * 8) = v;
}

// ---------------------------------------------------------------------------
// pack_a_tile: f32 features -> bf16 A-fragment order [group][kc][lane][8]
// Tile = 16 nodes x 128 k (4 kc chunks). LDS 8.3KB -> high occupancy.
// ---------------------------------------------------------------------------
template<int KT, int NKC>
__global__ __launch_bounds__(256) void pack_a_tile(
    const float* __restrict__ F, unsigned short* __restrict__ out)
{
    constexpr int TILES = NKC / 4;           // 4 for K=513, 1 for K=129
    __shared__ float sf[16][130];
    const int tid = threadIdx.x;
    const int g = blockIdx.x / TILES, t = blockIdx.x % TILES;
    const int nb = g * 16, k0 = t * 128;

#pragma unroll
    for (int i = 0; i < 8; ++i) {
        int idx = tid + i * 256;             // 0..2047
        int row = idx >> 7, k = idx & 127;
        sf[row][k] = F[(size_t)(nb + row) * KT + k0 + k];
    }
    __syncthreads();
    {
        int kcl = tid >> 6, l = tid & 63;
        int row = l & 15, kb = kcl * 32 + (l >> 4) * 8;
        bf16x8 o;
#pragma unroll
        for (int j = 0; j < 8; ++j) o[j] = (short)f2b(sf[row][kb + j]);
        *(bf16x8*)(out + ((size_t)(g * NKC + t * 4 + kcl) * 64 + l) * 8) = o;
    }
}

// ---------------------------------------------------------------------------
// Fusion half-pass: wave (rank r, k-half kh) accumulates its H=NKC/2 chunks.
// Ones-row init only on kh==0 (counted once per rank).
// ---------------------------------------------------------------------------
template<int K, int NKC>
__device__ __forceinline__ void fusion_pass_half(
    const unsigned short* __restrict__ ap, const unsigned short* __restrict__ wp,
    const float* __restrict__ W, int G, int r, int kh, int l, f32x4 (&acc)[4])
{
    constexpr int H = NKC / 2;
    const int c_lo = l & 15;
#pragma unroll
    for (int ct = 0; ct < 4; ++ct) {
        if (kh == 0) {
            float wi = W[((size_t)r * K + (K - 1)) * 64 + ct * 16 + c_lo];
            acc[ct] = f32x4{wi, wi, wi, wi};
        } else {
            acc[ct] = f32x4{0.f, 0.f, 0.f, 0.f};
        }
    }
    const unsigned short* ab = ap + (size_t)G * NKC * 512 + (size_t)kh * H * 512 + l * 8;
    const unsigned short* wb = wp + (size_t)kh * H * 8192 + r * 512 + l * 8;
#pragma unroll
    for (int kc = 0; kc < H; ++kc) {
        bf16x8 af = *(const bf16x8*)(ab + kc * 512);
        const unsigned short* wk = wb + (size_t)kc * 8192;
#pragma unroll
        for (int ct = 0; ct < 4; ++ct) {
            bf16x8 bf = *(const bf16x8*)(wk + ct * 2048);   // chunk = ct*4 + r
            acc[ct] = __builtin_amdgcn_mfma_f32_16x16x32_bf16(af, bf, acc[ct], 0, 0, 0);
        }
    }
}

// ---------------------------------------------------------------------------
// Fusion: block = 8 waves (rank r x k-half kh) on ONE 16-node group.
// Serial chunk chain per wave halves (36 -> 18); total waves double (TLP).
// LDS exchange combines k-halves per GEMM, then rank product + rank sum.
// ---------------------------------------------------------------------------
__global__ __launch_bounds__(512) void fusion_mfma(
    const unsigned short* __restrict__ apc, const unsigned short* __restrict__ apt,
    const unsigned short* __restrict__ apr,
    const unsigned short* __restrict__ wpc, const unsigned short* __restrict__ wpt,
    const unsigned short* __restrict__ wpr,
    const float* __restrict__ Wc, const float* __restrict__ Wt, const float* __restrict__ Wr,
    const float* __restrict__ fw, const float* __restrict__ fb,
    unsigned short* __restrict__ h0b)
{
    __shared__ float lds[8192];   // 32KB exchange buffer
    const int tid = threadIdx.x;
    const int w = tid >> 6, l = tid & 63;
    const int r = w & 3, kh = w >> 2;
    const int G = blockIdx.x;

    f32x4 pC[4], pT[4], pR[4];
    fusion_pass_half<129, 4>(apc, wpc, Wc, G, r, kh, l, pC);
    fusion_pass_half<513, 16>(apt, wpt, Wt, G, r, kh, l, pT);
    fusion_pass_half<513, 16>(apr, wpr, Wr, G, r, kh, l, pR);

    // combine k-halves: wave (r, kh=0) accumulates wave (r, kh=1)'s partials
    f32x4 fC[4], fT[4], fR[4];
#pragma unroll
    for (int ct = 0; ct < 4; ++ct)
        *(f32x4*)&lds[((w * 4 + ct) * 64 + l) * 4] = pC[ct];
    __syncthreads();
    if (kh == 0)
#pragma unroll
        for (int ct = 0; ct < 4; ++ct)
            fC[ct] = pC[ct] + *(const f32x4*)&lds[(((w + 4) * 4 + ct) * 64 + l) * 4];
    __syncthreads();
#pragma unroll
    for (int ct = 0; ct < 4; ++ct)
        *(f32x4*)&lds[((w * 4 + ct) * 64 + l) * 4] = pT[ct];
    __syncthreads();
    if (kh == 0)
#pragma unroll
        for (int ct = 0; ct < 4; ++ct)
            fT[ct] = pT[ct] + *(const f32x4*)&lds[(((w + 4) * 4 + ct) * 64 + l) * 4];
    __syncthreads();
#pragma unroll
    for (int ct = 0; ct < 4; ++ct)
        *(f32x4*)&lds[((w * 4 + ct) * 64 + l) * 4] = pR[ct];
    __syncthreads();
    if (kh == 0)
#pragma unroll
        for (int ct = 0; ct < 4; ++ct)
            fR[ct] = pR[ct] + *(const f32x4*)&lds[(((w + 4) * 4 + ct) * 64 + l) * 4];
    __syncthreads();

    // rank product -> LDS -> cross-rank sum (waves 0-3, ct = w)
    if (kh == 0) {
        const float fwr = fw[r];
#pragma unroll
        for (int ct = 0; ct < 4; ++ct) {
            f32x4 prod = fC[ct] * fT[ct] * fR[ct] * fwr;
            *(f32x4*)&lds[((r * 4 + ct) * 64 + l) * 4] = prod;
        }
    }
    __syncthreads();
    if (w < 4) {
        f32x4 s = *(const f32x4*)&lds[((0 * 4 + w) * 64 + l) * 4];
#pragma unroll
        for (int rr = 1; rr < 4; ++rr)
            s += *(const f32x4*)&lds[((rr * 4 + w) * 64 + l) * 4];
        const int c = w * 16 + (l & 15);
        const float fbc = fb[c];
#pragma unroll
        for (int q = 0; q < 4; ++q) {
            int n = G * 16 + (l >> 4) * 4 + q;
            float v = s[q] + fbc;
            v = v > 0.f ? v : expm1f(v);
            h0b[(size_t)n * 64 + c] = f2b(v);
        }
    }
}

// ---------------------------------------------------------------------------
// feat GEMM, register-streaming, ONE group per block, manual A prefetch +
// B rotation. Output HEAD-MINOR: featb[n][d*4+h].
// ---------------------------------------------------------------------------
template<int K>
__global__ __launch_bounds__(256) void gemm_reg(
    const unsigned short* __restrict__ Ab, const unsigned short* __restrict__ wp,
    unsigned short* __restrict__ featb)
{
    constexpr int NKC = K / 32;
    const int w = threadIdx.x >> 6, l = threadIdx.x & 63;
    const int nb = blockIdx.x * 16;

    f32x4 acc[4];
#pragma unroll
    for (int i = 0; i < 4; ++i) acc[i] = f32x4{0.f, 0.f, 0.f, 0.f};

    const unsigned short* abase = Ab + (size_t)(nb + (l & 15)) * K + (l >> 4) * 8;
    bf16x8 afs[NKC];
#pragma unroll
    for (int kc = 0; kc < NKC; ++kc)
        afs[kc] = *(const bf16x8*)(abase + kc * 32);

    bf16x8 bcur[4];
    {
        const unsigned short* wk = wp + (size_t)(0 * 16 + w * 4) * 512 + l * 8;
#pragma unroll
        for (int i = 0; i < 4; ++i) bcur[i] = *(const bf16x8*)(wk + i * 512);
    }
#pragma unroll
    for (int kc = 0; kc < NKC; ++kc) {
        bf16x8 bnxt[4];
        if (kc + 1 < NKC) {
            const unsigned short* wk = wp + ((size_t)(kc + 1) * 16 + w * 4) * 512 + l * 8;
#pragma unroll
            for (int i = 0; i < 4; ++i) bnxt[i] = *(const bf16x8*)(wk + i * 512);
        }
#pragma unroll
        for (int i = 0; i < 4; ++i)
            acc[i] = __builtin_amdgcn_mfma_f32_16x16x32_bf16(afs[kc], bcur[i], acc[i], 0, 0, 0);
        if (kc + 1 < NKC) {
#pragma unroll
            for (int i = 0; i < 4; ++i) bcur[i] = bnxt[i];
        }
    }
#pragma unroll
    for (int i = 0; i < 4; ++i) {
        int c = (w * 4 + i) * 16 + (l & 15);
        int dm = (c & 63) * 4 + (c >> 6);   // head-minor index
#pragma unroll
        for (int q = 0; q < 4; ++q) {
            int n = nb + (l >> 4) * 4 + q;
            featb[(size_t)n * 256 + dm] = f2b(acc[i][q]);
        }
    }
}

// ---------------------------------------------------------------------------
// el/er: one wave per node; head-minor feat -> single ushort4 load per lane.
// ---------------------------------------------------------------------------
__global__ __launch_bounds__(256) void elr_kernel(
    const unsigned short* __restrict__ featb,
    const float* __restrict__ al, const float* __restrict__ ar,
    float* __restrict__ el, float* __restrict__ er)
{
    int wid = (int)((blockIdx.x * (size_t)blockDim.x + threadIdx.x) >> 6);
    int lane = threadIdx.x & 63;
    if (wid >= NN) return;
    ushort4 f4 = *(const ushort4*)(featb + (size_t)wid * 256 + lane * 4);
    float x0 = b2f(f4.x), x1 = b2f(f4.y), x2 = b2f(f4.z), x3 = b2f(f4.w);
    float elh[4], erh[4];
    elh[0] = x0 * al[lane];        erh[0] = x0 * ar[lane];
    elh[1] = x1 * al[64 + lane];   erh[1] = x1 * ar[64 + lane];
    elh[2] = x2 * al[128 + lane];  erh[2] = x2 * ar[128 + lane];
    elh[3] = x3 * al[192 + lane];  erh[3] = x3 * ar[192 + lane];
#pragma unroll
    for (int off = 32; off; off >>= 1) {
#pragma unroll
        for (int h = 0; h < 4; ++h) {
            elh[h] += __shfl_xor(elh[h], off);
            erh[h] += __shfl_xor(erh[h], off);
        }
    }
    if (lane == 0) {
        *(float4*)(el + (size_t)wid * 4) = make_float4(elh[0], elh[1], elh[2], elh[3]);
        *(float4*)(er + (size_t)wid * 4) = make_float4(erh[0], erh[1], erh[2], erh[3]);
    }
}

// ---------------------------------------------------------------------------
// CSR build
// ---------------------------------------------------------------------------
__global__ void hist_kernel(const int* __restrict__ dst, int* __restrict__ cnt)
{
    int e = blockIdx.x * blockDim.x + threadIdx.x;
    if (e < EE) atomicAdd(&cnt[dst[e]], 1);
}

__global__ __launch_bounds__(1024) void scan_kernel(const int* __restrict__ cnt, int* __restrict__ offs)
{
    __shared__ int tmp[1024];
    const int t = threadIdx.x;
    const int C = (NN + 1023) / 1024;
    int lo = t * C, hi = min(lo + C, NN);
    int s = 0;
    for (int i = lo; i < hi; ++i) s += cnt[i];
    tmp[t] = s;
    __syncthreads();
    for (int off = 1; off < 1024; off <<= 1) {
        int v = (t >= off) ? tmp[t - off] : 0;
        __syncthreads();
        tmp[t] += v;
        __syncthreads();
    }
    int run = (t == 0) ? 0 : tmp[t - 1];
    for (int i = lo; i < hi; ++i) { offs[i] = run; run += cnt[i]; }
    if (t == 1023) offs[NN] = tmp[1023];
}

__global__ void scatter_kernel(const int* __restrict__ dst, const int* __restrict__ offs,
                               int* __restrict__ cur, int* __restrict__ esort)
{
    int e = blockIdx.x * blockDim.x + threadIdx.x;
    if (e < EE) {
        int d = dst[e];
        int p = offs[d] + atomicAdd(&cur[d], 1);
        esort[p] = e;
    }
}

// ---------------------------------------------------------------------------
// edge_prep: CSR-ordered logits + CSR-ordered src index.
// ---------------------------------------------------------------------------
__global__ void edge_prep(const int* __restrict__ esort, const int* __restrict__ src,
                          const int* __restrict__ dst,
                          const float* __restrict__ el, const float* __restrict__ er,
                          float4* __restrict__ eesort, int* __restrict__ srcsort)
{
    int p = blockIdx.x * blockDim.x + threadIdx.x;
    if (p >= EE) return;
    int e = esort[p];
    int s = src[e], d = dst[e];
    srcsort[p] = s;
    float4 l4 = *(const float4*)(el + (size_t)s * 4);
    float4 r4 = *(const float4*)(er + (size_t)d * 4);
    eesort[p] = make_float4(lrelu(l4.x + r4.x), lrelu(l4.y + r4.y),
                            lrelu(l4.z + r4.z), lrelu(l4.w + r4.w));
}

// ---------------------------------------------------------------------------
// Per-dst softmax + aggregation. One wave per node.
// Pass A: strided max. Pass B: strided exp writeback + z-sum.
// Pass C: serial edges x4-unrolled, weights ready-made, 1/z deferred.
// ---------------------------------------------------------------------------
template <int RESID, int WMZ, int WB16, int WF32>
__global__ __launch_bounds__(256) void gat_agg(
    const int* __restrict__ srcsort, const int* __restrict__ offs,
    const unsigned short* __restrict__ featb, float4* __restrict__ eesort,
    const unsigned short* __restrict__ residb, const float* __restrict__ bias,
    float* __restrict__ out, unsigned short* __restrict__ outb,
    float4* __restrict__ mbuf, float4* __restrict__ zbuf)
{
    int n = (int)((blockIdx.x * (size_t)blockDim.x + threadIdx.x) >> 6);
    int lane = threadIdx.x & 63;
    if (n >= NN) return;
    int s0 = offs[n], s1 = offs[n + 1];

    float m0 = -1e30f, m1 = -1e30f, m2 = -1e30f, m3 = -1e30f;
    for (int p = s0 + lane; p < s1; p += 64) {
        float4 v = eesort[p];
        m0 = fmaxf(m0, v.x); m1 = fmaxf(m1, v.y);
        m2 = fmaxf(m2, v.z); m3 = fmaxf(m3, v.w);
    }
#pragma unroll
    for (int off = 32; off; off >>= 1) {
        m0 = fmaxf(m0, __shfl_xor(m0, off));
        m1 = fmaxf(m1, __shfl_xor(m1, off));
        m2 = fmaxf(m2, __shfl_xor(m2, off));
        m3 = fmaxf(m3, __shfl_xor(m3, off));
    }

    float z0 = 0.f, z1 = 0.f, z2 = 0.f, z3 = 0.f;
    for (int p = s0 + lane; p < s1; p += 64) {
        float4 v = eesort[p];
        v.x = expf(v.x - m0); v.y = expf(v.y - m1);
        v.z = expf(v.z - m2); v.w = expf(v.w - m3);
        eesort[p] = v;
        z0 += v.x; z1 += v.y; z2 += v.z; z3 += v.w;
    }
    __threadfence_block();   // make lane-strided writebacks visible wave-wide
#pragma unroll
    for (int off = 32; off; off >>= 1) {
        z0 += __shfl_xor(z0, off);
        z1 += __shfl_xor(z1, off);
        z2 += __shfl_xor(z2, off);
        z3 += __shfl_xor(z3, off);
    }
    float i0 = z0 > 0.f ? 1.f / z0 : 0.f;
    float i1 = z1 > 0.f ? 1.f / z1 : 0.f;
    float i2 = z2 > 0.f ? 1.f / z2 : 0.f;
    float i3 = z3 > 0.f ? 1.f / z3 : 0.f;
    if (WMZ && lane == 0) {
        mbuf[n] = make_float4(m0, m1, m2, m3);
        zbuf[n] = make_float4(i0, i1, i2, i3);
    }

    float a0 = 0.f, a1 = 0.f, a2 = 0.f, a3 = 0.f;
    float c0 = 0.f, c1 = 0.f, c2 = 0.f, c3 = 0.f;
    int p = s0;
    for (; p + 3 < s1; p += 4) {
        float4 wA = eesort[p],     wB = eesort[p + 1];
        float4 wC = eesort[p + 2], wD = eesort[p + 3];
        int sA = srcsort[p],     sB = srcsort[p + 1];
        int sC = srcsort[p + 2], sD = srcsort[p + 3];
        ushort4 fA = *(const ushort4*)(featb + (size_t)sA * 256 + lane * 4);
        ushort4 fB = *(const ushort4*)(featb + (size_t)sB * 256 + lane * 4);
        ushort4 fC = *(const ushort4*)(featb + (size_t)sC * 256 + lane * 4);
        ushort4 fD = *(const ushort4*)(featb + (size_t)sD * 256 + lane * 4);
        a0 += wA.x * b2f(fA.x);  c0 += wB.x * b2f(fB.x);
        a1 += wA.y * b2f(fA.y);  c1 += wB.y * b2f(fB.y);
        a2 += wA.z * b2f(fA.z);  c2 += wB.z * b2f(fB.z);
        a3 += wA.w * b2f(fA.w);  c3 += wB.w * b2f(fB.w);
        a0 += wC.x * b2f(fC.x);  c0 += wD.x * b2f(fD.x);
        a1 += wC.y * b2f(fC.y);  c1 += wD.y * b2f(fD.y);
        a2 += wC.z * b2f(fC.z);  c2 += wD.z * b2f(fD.z);
        a3 += wC.w * b2f(fC.w);  c3 += wD.w * b2f(fD.w);
    }
    for (; p < s1; ++p) {
        float4 wA = eesort[p];
        int sA = srcsort[p];
        ushort4 fA = *(const ushort4*)(featb + (size_t)sA * 256 + lane * 4);
        a0 += wA.x * b2f(fA.x);
        a1 += wA.y * b2f(fA.y);
        a2 += wA.z * b2f(fA.z);
        a3 += wA.w * b2f(fA.w);
    }
    a0 += c0; a1 += c1; a2 += c2; a3 += c3;

    float o0 = a0 * i0 + bias[lane];
    float o1 = a1 * i1 + bias[64 + lane];
    float o2 = a2 * i2 + bias[128 + lane];
    float o3 = a3 * i3 + bias[192 + lane];
    if (RESID) {
        ushort4 rp = *(const ushort4*)(residb + (size_t)n * 256 + lane * 4);
        o0 += b2f(rp.x); o1 += b2f(rp.y); o2 += b2f(rp.z); o3 += b2f(rp.w);
    }
    if (WF32) {
        float* op = out + (size_t)n * 256;
        op[lane] = o0;
        op[64 + lane] = o1;
        op[128 + lane] = o2;
        op[192 + lane] = o3;
    }
    if (WB16) {
        ushort4 ob;
        ob.x = f2b(o0); ob.y = f2b(o1); ob.z = f2b(o2); ob.w = f2b(o3);
        *(ushort4*)(outb + (size_t)n * 256 + lane * 4) = ob;
    }
}

// ---------------------------------------------------------------------------
// att_final: att[e] = exp(lrelu(el[src]+er[dst]) - m[dst]) * i[dst]
// ---------------------------------------------------------------------------
__global__ void att_final(const int* __restrict__ src, const int* __restrict__ dst,
                          const float* __restrict__ el, const float* __restrict__ er,
                          const float4* __restrict__ mbuf, const float4* __restrict__ zbuf,
                          float4* __restrict__ att)
{
    int e = blockIdx.x * blockDim.x + threadIdx.x;
    if (e >= EE) return;
    int s = src[e], d = dst[e];
    float4 l4 = *(const float4*)(el + (size_t)s * 4);
    float4 r4 = *(const float4*)(er + (size_t)d * 4);
    float4 m4 = mbuf[d], zi = zbuf[d];
    att[e] = make_float4(expf(lrelu(l4.x + r4.x) - m4.x) * zi.x,
                         expf(lrelu(l4.y + r4.y) - m4.y) * zi.y,
                         expf(lrelu(l4.z + r4.z) - m4.z) * zi.z,
                         expf(lrelu(l4.w + r4.w) - m4.w) * zi.w);
}

// ---------------------------------------------------------------------------
extern "C" void kernel_launch(void* const* d_in, const int* in_sizes, int n_in,
                              void* d_out, int out_size, void* d_ws, size_t ws_size,
                              hipStream_t stream)
{
    const int*   src = (const int*)d_in[0];
    const int*   dst = (const int*)d_in[1];
    const float* hc  = (const float*)d_in[2];
    const float* ht  = (const float*)d_in[3];
    const float* hr  = (const float*)d_in[4];
    const float* Wc  = (const float*)d_in[5];
    const float* Wt  = (const float*)d_in[6];
    const float* Wr  = (const float*)d_in[7];
    const float* fw  = (const float*)d_in[8];
    const float* fb  = (const float*)d_in[9];
    const float* W0  = (const float*)d_in[10];
    const float* al0 = (const float*)d_in[11];
    const float* ar0 = (const float*)d_in[12];
    const float* b0  = (const float*)d_in[13];
    const float* W1  = (const float*)d_in[14];
    const float* al1 = (const float*)d_in[15];
    const float* ar1 = (const float*)d_in[16];
    const float* b1  = (const float*)d_in[17];

    // workspace layout (bytes); round-2 proved ws_size >= 69,200,064
    char* ws = (char*)d_ws;
    unsigned short* h0b   = (unsigned short*)(ws);               // N*64  bf16 :  6,400,000
    unsigned short* h1b   = (unsigned short*)(ws + 6400000);     // N*256 bf16 : 25,600,000 (head-minor)
    unsigned short* featb = (unsigned short*)(ws + 32000000);    // N*256 bf16 : 25,600,000 (head-minor)
    float* el    = (float*)(ws + 57600000);                      //    800,000
    float* er    = (float*)(ws + 58400000);                      //    800,000
    int*   cnt   = (int*)  (ws + 59200000);                      //    200,000
    int*   offs  = (int*)  (ws + 59400000);                      //    200,064 (padded)
    int*   esort = (int*)  (ws + 59600128);                      //  3,200,000
    unsigned short* wpc = (unsigned short*)(ws + 62800128);      //  4*16KB =  65,536
    unsigned short* wpt = (unsigned short*)(ws + 62865664);      // 16*16KB = 262,144
    unsigned short* wpr = (unsigned short*)(ws + 63127808);      // 16*16KB = 262,144
    unsigned short* wp0 = (unsigned short*)(ws + 63389952);      //  2*16KB =  32,768
    unsigned short* wp1 = (unsigned short*)(ws + 63422720);      //  8*16KB = 131,072
    float4* mbuf = (float4*)(ws + 63553792);                     //    800,000
    float4* zbuf = (float4*)(ws + 64353792);                     //    800,000
    int* srcsort = (int*)  (ws + 65153792);                      //  3,200,000
    if (ws_size < 68353792ull) return;                           // end of layout

    float* outh = (float*)d_out;                       // N*256 final h
    float4* atto = (float4*)(outh + (size_t)NN * 256); // E*4 att region

    // A-pack overlays (live only during fusion)
    unsigned short* apt = (unsigned short*)d_out;                     // 51,200,000
    unsigned short* apc = (unsigned short*)((char*)d_out + 51200000); // 12,800,000
    unsigned short* apr = (unsigned short*)(ws + 6400000);            // 51,200,000

    // weight packing
    pack_w_fusion<<<(4 * 16 * 64 + 255) / 256, 256, 0, stream>>>(Wc, wpc, 129, 4);
    pack_w_fusion<<<(16 * 16 * 64 + 255) / 256, 256, 0, stream>>>(Wt, wpt, 513, 16);
    pack_w_fusion<<<(16 * 16 * 64 + 255) / 256, 256, 0, stream>>>(Wr, wpr, 513, 16);
    pack_w_gemm<0><<<(2 * 16 * 64 + 255) / 256, 256, 0, stream>>>(W0, wp0, 64, 256);
    pack_w_gemm<1><<<(8 * 16 * 64 + 255) / 256, 256, 0, stream>>>(W1, wp1, 256, 256);

    // F1: feature packs (f32 -> bf16 A-fragment order), 128-k tiles
    pack_a_tile<129, 4><<<NG * 1, 256, 0, stream>>>(hc, apc);
    pack_a_tile<513, 16><<<NG * 4, 256, 0, stream>>>(ht, apt);
    pack_a_tile<513, 16><<<NG * 4, 256, 0, stream>>>(hr, apr);

    // F2: trilinear fusion (rank x k-half split, 8 waves/block)
    fusion_mfma<<<NG, 512, 0, stream>>>(apc, apt, apr, wpc, wpt, wpr,
                                        Wc, Wt, Wr, fw, fb, h0b);

    // CSR by dst
    hipMemsetAsync(cnt, 0, NN * sizeof(int), stream);
    hist_kernel<<<(EE + 255) / 256, 256, 0, stream>>>(dst, cnt);
    scan_kernel<<<1, 1024, 0, stream>>>(cnt, offs);
    hipMemsetAsync(cnt, 0, NN * sizeof(int), stream);
    scatter_kernel<<<(EE + 255) / 256, 256, 0, stream>>>(dst, offs, cnt, esort);

    // GAT layer 0: output only bf16 h1b (head-minor)
    gemm_reg<64><<<NG, 256, 0, stream>>>(h0b, wp0, featb);
    elr_kernel<<<(NN * 64 + 255) / 256, 256, 0, stream>>>(featb, al0, ar0, el, er);
    edge_prep<<<(EE + 255) / 256, 256, 0, stream>>>(esort, src, dst, el, er, atto, srcsort);
    gat_agg<0, 0, 1, 0><<<(NN * 64 + 255) / 256, 256, 0, stream>>>(
        srcsort, offs, featb, atto, nullptr, b0, nullptr, h1b, nullptr, nullptr);

    // GAT layer 1: residual from bf16 h1b; f32 out to d_out
    gemm_reg<256><<<NG, 256, 0, stream>>>(h1b, wp1, featb);
    elr_kernel<<<(NN * 64 + 255) / 256, 256, 0, stream>>>(featb, al1, ar1, el, er);
    edge_prep<<<(EE + 255) / 256, 256, 0, stream>>>(esort, src, dst, el, er, atto, srcsort);
    gat_agg<1, 1, 0, 1><<<(NN * 64 + 255) / 256, 256, 0, stream>>>(
        srcsort, offs, featb, atto, h1b, b1, outh, nullptr, mbuf, zbuf);
    att_final<<<(EE + 255) / 256, 256, 0, stream>>>(src, dst, el, er, mbuf, zbuf, atto);
}

// Round 14
// 578.412 us; speedup vs baseline: 1.1020x; 1.1020x over previous
//
#include <hip/hip_runtime.h>
#include <math.h>

#define NN 50000
#define EE 800000
#define NEG 0.2f
#define NG (NN / 16)   // 3125 node groups

using f32x4  = __attribute__((ext_vector_type(4))) float;
using bf16x8 = __attribute__((ext_vector_type(8))) short;

__device__ __forceinline__ float lrelu(float x){ return x > 0.f ? x : NEG*x; }

__device__ __forceinline__ unsigned short f2b(float f){
    unsigned int u = __float_as_uint(f);
    return (unsigned short)((u + 0x7FFFu + ((u >> 16) & 1u)) >> 16);  // RNE
}
__device__ __forceinline__ float b2f(unsigned short h){
    return __uint_as_float(((unsigned int)h) << 16);
}

// ---------------------------------------------------------------------------
// Weight packers (fragment-order bf16).
// Fusion: chunk = ct*4 + r. k < K-1 only (ones-row handled via acc init).
// ---------------------------------------------------------------------------
__global__ void pack_w_fusion(const float* __restrict__ W, unsigned short* __restrict__ out,
                              int K, int NKC)
{
    int u = blockIdx.x * blockDim.x + threadIdx.x;
    if (u >= NKC * 16 * 64) return;
    int l = u & 63, chunk = (u >> 6) & 15, kc = u >> 10;
    int ct = chunk >> 2, r = chunk & 3;
    int c = ct * 16 + (l & 15);
    int kb = kc * 32 + (l >> 4) * 8;
    bf16x8 v;
#pragma unroll
    for (int j = 0; j < 8; ++j)
        v[j] = (short)f2b(W[((size_t)r * K + kb + j) * 64 + c]);
    *(bf16x8*)(out + (size_t)u * 8) = v;
}

// GEMM weights: chunk = ct (C/16 chunks per kc); K multiple of 32.
// PERM=1: A rows are stored head-minor (k_store = d*4+h <-> k_orig = h*64+d).
template<int PERM>
__global__ void pack_w_gemm(const float* __restrict__ W, unsigned short* __restrict__ out,
                            int K, int C)
{
    int NCH = C / 16;
    int total = (K / 32) * NCH * 64;
    int u = blockIdx.x * blockDim.x + threadIdx.x;
    if (u >= total) return;
    int l = u & 63, ch = (u >> 6) % NCH, kc = u / (64 * NCH);
    int c = ch * 16 + (l & 15);
    int kb = kc * 32 + (l >> 4) * 8;
    bf16x8 v;
#pragma unroll
    for (int j = 0; j < 8; ++j) {
        int k = kb + j;
        int ko = PERM ? ((k & 3) * 64 + (k >> 2)) : k;
        v[j] = (short)f2b(W[(size_t)ko * C + c]);
    }
    *(bf16x8*)(out + (size_t)u * 8) = v;
}

// ---------------------------------------------------------------------------
// pack_a_tile: f32 features -> bf16 A-fragment order [group][kc][lane][8]
// Tile = 16 nodes x 128 k (4 kc chunks). LDS 8.3KB -> high occupancy.
// ---------------------------------------------------------------------------
template<int KT, int NKC>
__global__ __launch_bounds__(256) void pack_a_tile(
    const float* __restrict__ F, unsigned short* __restrict__ out)
{
    constexpr int TILES = NKC / 4;           // 4 for K=513, 1 for K=129
    __shared__ float sf[16][130];
    const int tid = threadIdx.x;
    const int g = blockIdx.x / TILES, t = blockIdx.x % TILES;
    const int nb = g * 16, k0 = t * 128;

#pragma unroll
    for (int i = 0; i < 8; ++i) {
        int idx = tid + i * 256;             // 0..2047
        int row = idx >> 7, k = idx & 127;
        sf[row][k] = F[(size_t)(nb + row) * KT + k0 + k];
    }
    __syncthreads();
    {
        int kcl = tid >> 6, l = tid & 63;
        int row = l & 15, kb = kcl * 32 + (l >> 4) * 8;
        bf16x8 o;
#pragma unroll
        for (int j = 0; j < 8; ++j) o[j] = (short)f2b(sf[row][kb + j]);
        *(bf16x8*)(out + ((size_t)(g * NKC + t * 4 + kcl) * 64 + l) * 8) = o;
    }
}

// ---------------------------------------------------------------------------
// Fusion, rank-split (R9-exact, measured best 94us): block = 4 waves on ONE
// 16-node group; wave w = rank w. Per chunk: 1 A-frag + 4 B-frags + 4 MFMA.
// acc initialized from the ones-row W[w][K-1][c] (exact f32).
// ---------------------------------------------------------------------------
template<int K, int NKC>
__device__ __forceinline__ void fusion_pass_rank(
    const unsigned short* __restrict__ ap, const unsigned short* __restrict__ wp,
    const float* __restrict__ W, int G, int w, int l, f32x4 (&acc)[4])
{
    const int c_lo = l & 15;
#pragma unroll
    for (int ct = 0; ct < 4; ++ct) {
        float wi = W[((size_t)w * K + (K - 1)) * 64 + ct * 16 + c_lo];
        acc[ct] = f32x4{wi, wi, wi, wi};
    }
    const unsigned short* abase = ap + (size_t)G * NKC * 512 + l * 8;
#pragma unroll
    for (int kc = 0; kc < NKC; ++kc) {
        bf16x8 af = *(const bf16x8*)(abase + kc * 512);
        const unsigned short* wk = wp + (size_t)kc * 8192 + w * 512 + l * 8;
#pragma unroll
        for (int ct = 0; ct < 4; ++ct) {
            bf16x8 bf = *(const bf16x8*)(wk + ct * 2048);   // chunk = ct*4 + w
            acc[ct] = __builtin_amdgcn_mfma_f32_16x16x32_bf16(af, bf, acc[ct], 0, 0, 0);
        }
    }
}

__global__ __launch_bounds__(256) void fusion_mfma(
    const unsigned short* __restrict__ apc, const unsigned short* __restrict__ apt,
    const unsigned short* __restrict__ apr,
    const unsigned short* __restrict__ wpc, const unsigned short* __restrict__ wpt,
    const unsigned short* __restrict__ wpr,
    const float* __restrict__ Wc, const float* __restrict__ Wt, const float* __restrict__ Wr,
    const float* __restrict__ fw, const float* __restrict__ fb,
    unsigned short* __restrict__ h0b)
{
    __shared__ float lds[4096];   // 16KB rank-exchange
    const int w = threadIdx.x >> 6, l = threadIdx.x & 63;
    const int G = blockIdx.x;

    f32x4 prod[4], acc[4];
    fusion_pass_rank<129, 4>(apc, wpc, Wc, G, w, l, acc);
#pragma unroll
    for (int ct = 0; ct < 4; ++ct) prod[ct] = acc[ct];
    fusion_pass_rank<513, 16>(apt, wpt, Wt, G, w, l, acc);
#pragma unroll
    for (int ct = 0; ct < 4; ++ct) prod[ct] *= acc[ct];
    fusion_pass_rank<513, 16>(apr, wpr, Wr, G, w, l, acc);
    const float fww = fw[w];
#pragma unroll
    for (int ct = 0; ct < 4; ++ct) {
        prod[ct] *= acc[ct];
        *(f32x4*)&lds[((w * 4 + ct) * 64 + l) * 4] = prod[ct] * fww;
    }
    __syncthreads();

    // wave w sums the 4 ranks for col-tile ct = w
    f32x4 s = *(const f32x4*)&lds[((0 * 4 + w) * 64 + l) * 4];
#pragma unroll
    for (int r = 1; r < 4; ++r)
        s += *(const f32x4*)&lds[((r * 4 + w) * 64 + l) * 4];

    const int c = w * 16 + (l & 15);
    const float fbc = fb[c];
#pragma unroll
    for (int q = 0; q < 4; ++q) {
        int n = G * 16 + (l >> 4) * 4 + q;
        float v = s[q] + fbc;
        v = v > 0.f ? v : expm1f(v);
        h0b[(size_t)n * 64 + c] = f2b(v);
    }
}

// ---------------------------------------------------------------------------
// feat GEMM with FUSED el/er epilogue. Wave w == head w: its acc covers all
// 64 features of head w for the block's 16 nodes -> el/er via 4 fma/lane +
// 16-lane shuffle reduce (replaces the separate elr_kernel entirely).
// Output feat HEAD-MINOR: featb[n][d*4+h].
// ---------------------------------------------------------------------------
template<int K>
__global__ __launch_bounds__(256) void gemm_reg(
    const unsigned short* __restrict__ Ab, const unsigned short* __restrict__ wp,
    const float* __restrict__ al, const float* __restrict__ ar,
    unsigned short* __restrict__ featb,
    float* __restrict__ el, float* __restrict__ er)
{
    constexpr int NKC = K / 32;
    const int w = threadIdx.x >> 6, l = threadIdx.x & 63;
    const int nb = blockIdx.x * 16;

    f32x4 acc[4];
#pragma unroll
    for (int i = 0; i < 4; ++i) acc[i] = f32x4{0.f, 0.f, 0.f, 0.f};

    const unsigned short* abase = Ab + (size_t)(nb + (l & 15)) * K + (l >> 4) * 8;
    bf16x8 afs[NKC];
#pragma unroll
    for (int kc = 0; kc < NKC; ++kc)
        afs[kc] = *(const bf16x8*)(abase + kc * 32);

    bf16x8 bcur[4];
    {
        const unsigned short* wk = wp + (size_t)(0 * 16 + w * 4) * 512 + l * 8;
#pragma unroll
        for (int i = 0; i < 4; ++i) bcur[i] = *(const bf16x8*)(wk + i * 512);
    }
#pragma unroll
    for (int kc = 0; kc < NKC; ++kc) {
        bf16x8 bnxt[4];
        if (kc + 1 < NKC) {
            const unsigned short* wk = wp + ((size_t)(kc + 1) * 16 + w * 4) * 512 + l * 8;
#pragma unroll
            for (int i = 0; i < 4; ++i) bnxt[i] = *(const bf16x8*)(wk + i * 512);
        }
#pragma unroll
        for (int i = 0; i < 4; ++i)
            acc[i] = __builtin_amdgcn_mfma_f32_16x16x32_bf16(afs[kc], bcur[i], acc[i], 0, 0, 0);
        if (kc + 1 < NKC) {
#pragma unroll
            for (int i = 0; i < 4; ++i) bcur[i] = bnxt[i];
        }
    }

    // feat store (head-minor)
#pragma unroll
    for (int i = 0; i < 4; ++i) {
        int c = (w * 4 + i) * 16 + (l & 15);
        int dm = (c & 63) * 4 + (c >> 6);
#pragma unroll
        for (int q = 0; q < 4; ++q) {
            int n = nb + (l >> 4) * 4 + q;
            featb[(size_t)n * 256 + dm] = f2b(acc[i][q]);
        }
    }

    // fused el/er for head h = w
    float pel[4] = {0.f, 0.f, 0.f, 0.f};
    float per_[4] = {0.f, 0.f, 0.f, 0.f};
#pragma unroll
    for (int i = 0; i < 4; ++i) {
        int d = i * 16 + (l & 15);
        float av = al[w * 64 + d];
        float rv = ar[w * 64 + d];
#pragma unroll
        for (int q = 0; q < 4; ++q) {
            pel[q] += acc[i][q] * av;
            per_[q] += acc[i][q] * rv;
        }
    }
#pragma unroll
    for (int off = 1; off <= 8; off <<= 1) {
#pragma unroll
        for (int q = 0; q < 4; ++q) {
            pel[q] += __shfl_xor(pel[q], off);
            per_[q] += __shfl_xor(per_[q], off);
        }
    }
    int qsel = l & 15;
    if (qsel < 4) {
        float ev = qsel == 0 ? pel[0] : qsel == 1 ? pel[1] : qsel == 2 ? pel[2] : pel[3];
        float rv = qsel == 0 ? per_[0] : qsel == 1 ? per_[1] : qsel == 2 ? per_[2] : per_[3];
        int n = nb + (l >> 4) * 4 + qsel;
        el[(size_t)n * 4 + w] = ev;
        er[(size_t)n * 4 + w] = rv;
    }
}

// ---------------------------------------------------------------------------
// CSR build
// ---------------------------------------------------------------------------
__global__ void hist_kernel(const int* __restrict__ dst, int* __restrict__ cnt)
{
    int e = blockIdx.x * blockDim.x + threadIdx.x;
    if (e < EE) atomicAdd(&cnt[dst[e]], 1);
}

__global__ __launch_bounds__(1024) void scan_kernel(const int* __restrict__ cnt, int* __restrict__ offs)
{
    __shared__ int tmp[1024];
    const int t = threadIdx.x;
    const int C = (NN + 1023) / 1024;
    int lo = t * C, hi = min(lo + C, NN);
    int s = 0;
    for (int i = lo; i < hi; ++i) s += cnt[i];
    tmp[t] = s;
    __syncthreads();
    for (int off = 1; off < 1024; off <<= 1) {
        int v = (t >= off) ? tmp[t - off] : 0;
        __syncthreads();
        tmp[t] += v;
        __syncthreads();
    }
    int run = (t == 0) ? 0 : tmp[t - 1];
    for (int i = lo; i < hi; ++i) { offs[i] = run; run += cnt[i]; }
    if (t == 1023) offs[NN] = tmp[1023];
}

__global__ void scatter_kernel(const int* __restrict__ dst, const int* __restrict__ offs,
                               int* __restrict__ cur, int* __restrict__ esort)
{
    int e = blockIdx.x * blockDim.x + threadIdx.x;
    if (e < EE) {
        int d = dst[e];
        int p = offs[d] + atomicAdd(&cur[d], 1);
        esort[p] = e;
    }
}

// ---------------------------------------------------------------------------
// edge_prep: CSR-ordered logits + CSR-ordered src index.
// ---------------------------------------------------------------------------
__global__ void edge_prep(const int* __restrict__ esort, const int* __restrict__ src,
                          const int* __restrict__ dst,
                          const float* __restrict__ el, const float* __restrict__ er,
                          float4* __restrict__ eesort, int* __restrict__ srcsort)
{
    int p = blockIdx.x * blockDim.x + threadIdx.x;
    if (p >= EE) return;
    int e = esort[p];
    int s = src[e], d = dst[e];
    srcsort[p] = s;
    float4 l4 = *(const float4*)(el + (size_t)s * 4);
    float4 r4 = *(const float4*)(er + (size_t)d * 4);
    eesort[p] = make_float4(lrelu(l4.x + r4.x), lrelu(l4.y + r4.y),
                            lrelu(l4.z + r4.z), lrelu(l4.w + r4.w));
}

// ---------------------------------------------------------------------------
// Per-dst softmax + aggregation. One wave per node.
// Pass A: strided max. Pass B: strided exp writeback + z-sum.
// Pass C: serial edges x4-unrolled, weights ready-made, 1/z deferred.
// ---------------------------------------------------------------------------
template <int RESID, int WMZ, int WB16, int WF32>
__global__ __launch_bounds__(256) void gat_agg(
    const int* __restrict__ srcsort, const int* __restrict__ offs,
    const unsigned short* __restrict__ featb, float4* __restrict__ eesort,
    const unsigned short* __restrict__ residb, const float* __restrict__ bias,
    float* __restrict__ out, unsigned short* __restrict__ outb,
    float4* __restrict__ mbuf, float4* __restrict__ zbuf)
{
    int n = (int)((blockIdx.x * (size_t)blockDim.x + threadIdx.x) >> 6);
    int lane = threadIdx.x & 63;
    if (n >= NN) return;
    int s0 = offs[n], s1 = offs[n + 1];

    float m0 = -1e30f, m1 = -1e30f, m2 = -1e30f, m3 = -1e30f;
    for (int p = s0 + lane; p < s1; p += 64) {
        float4 v = eesort[p];
        m0 = fmaxf(m0, v.x); m1 = fmaxf(m1, v.y);
        m2 = fmaxf(m2, v.z); m3 = fmaxf(m3, v.w);
    }
#pragma unroll
    for (int off = 32; off; off >>= 1) {
        m0 = fmaxf(m0, __shfl_xor(m0, off));
        m1 = fmaxf(m1, __shfl_xor(m1, off));
        m2 = fmaxf(m2, __shfl_xor(m2, off));
        m3 = fmaxf(m3, __shfl_xor(m3, off));
    }

    float z0 = 0.f, z1 = 0.f, z2 = 0.f, z3 = 0.f;
    for (int p = s0 + lane; p < s1; p += 64) {
        float4 v = eesort[p];
        v.x = expf(v.x - m0); v.y = expf(v.y - m1);
        v.z = expf(v.z - m2); v.w = expf(v.w - m3);
        eesort[p] = v;
        z0 += v.x; z1 += v.y; z2 += v.z; z3 += v.w;
    }
    __threadfence_block();   // make lane-strided writebacks visible wave-wide
#pragma unroll
    for (int off = 32; off; off >>= 1) {
        z0 += __shfl_xor(z0, off);
        z1 += __shfl_xor(z1, off);
        z2 += __shfl_xor(z2, off);
        z3 += __shfl_xor(z3, off);
    }
    float i0 = z0 > 0.f ? 1.f / z0 : 0.f;
    float i1 = z1 > 0.f ? 1.f / z1 : 0.f;
    float i2 = z2 > 0.f ? 1.f / z2 : 0.f;
    float i3 = z3 > 0.f ? 1.f / z3 : 0.f;
    if (WMZ && lane == 0) {
        mbuf[n] = make_float4(m0, m1, m2, m3);
        zbuf[n] = make_float4(i0, i1, i2, i3);
    }

    float a0 = 0.f, a1 = 0.f, a2 = 0.f, a3 = 0.f;
    float c0 = 0.f, c1 = 0.f, c2 = 0.f, c3 = 0.f;
    int p = s0;
    for (; p + 3 < s1; p += 4) {
        float4 wA = eesort[p],     wB = eesort[p + 1];
        float4 wC = eesort[p + 2], wD = eesort[p + 3];
        int sA = srcsort[p],     sB = srcsort[p + 1];
        int sC = srcsort[p + 2], sD = srcsort[p + 3];
        ushort4 fA = *(const ushort4*)(featb + (size_t)sA * 256 + lane * 4);
        ushort4 fB = *(const ushort4*)(featb + (size_t)sB * 256 + lane * 4);
        ushort4 fC = *(const ushort4*)(featb + (size_t)sC * 256 + lane * 4);
        ushort4 fD = *(const ushort4*)(featb + (size_t)sD * 256 + lane * 4);
        a0 += wA.x * b2f(fA.x);  c0 += wB.x * b2f(fB.x);
        a1 += wA.y * b2f(fA.y);  c1 += wB.y * b2f(fB.y);
        a2 += wA.z * b2f(fA.z);  c2 += wB.z * b2f(fB.z);
        a3 += wA.w * b2f(fA.w);  c3 += wB.w * b2f(fB.w);
        a0 += wC.x * b2f(fC.x);  c0 += wD.x * b2f(fD.x);
        a1 += wC.y * b2f(fC.y);  c1 += wD.y * b2f(fD.y);
        a2 += wC.z * b2f(fC.z);  c2 += wD.z * b2f(fD.z);
        a3 += wC.w * b2f(fC.w);  c3 += wD.w * b2f(fD.w);
    }
    for (; p < s1; ++p) {
        float4 wA = eesort[p];
        int sA = srcsort[p];
        ushort4 fA = *(const ushort4*)(featb + (size_t)sA * 256 + lane * 4);
        a0 += wA.x * b2f(fA.x);
        a1 += wA.y * b2f(fA.y);
        a2 += wA.z * b2f(fA.z);
        a3 += wA.w * b2f(fA.w);
    }
    a0 += c0; a1 += c1; a2 += c2; a3 += c3;

    float o0 = a0 * i0 + bias[lane];
    float o1 = a1 * i1 + bias[64 + lane];
    float o2 = a2 * i2 + bias[128 + lane];
    float o3 = a3 * i3 + bias[192 + lane];
    if (RESID) {
        ushort4 rp = *(const ushort4*)(residb + (size_t)n * 256 + lane * 4);
        o0 += b2f(rp.x); o1 += b2f(rp.y); o2 += b2f(rp.z); o3 += b2f(rp.w);
    }
    if (WF32) {
        float* op = out + (size_t)n * 256;
        op[lane] = o0;
        op[64 + lane] = o1;
        op[128 + lane] = o2;
        op[192 + lane] = o3;
    }
    if (WB16) {
        ushort4 ob;
        ob.x = f2b(o0); ob.y = f2b(o1); ob.z = f2b(o2); ob.w = f2b(o3);
        *(ushort4*)(outb + (size_t)n * 256 + lane * 4) = ob;
    }
}

// ---------------------------------------------------------------------------
// att_final: att[e] = exp(lrelu(el[src]+er[dst]) - m[dst]) * i[dst]
// ---------------------------------------------------------------------------
__global__ void att_final(const int* __restrict__ src, const int* __restrict__ dst,
                          const float* __restrict__ el, const float* __restrict__ er,
                          const float4* __restrict__ mbuf, const float4* __restrict__ zbuf,
                          float4* __restrict__ att)
{
    int e = blockIdx.x * blockDim.x + threadIdx.x;
    if (e >= EE) return;
    int s = src[e], d = dst[e];
    float4 l4 = *(const float4*)(el + (size_t)s * 4);
    float4 r4 = *(const float4*)(er + (size_t)d * 4);
    float4 m4 = mbuf[d], zi = zbuf[d];
    att[e] = make_float4(expf(lrelu(l4.x + r4.x) - m4.x) * zi.x,
                         expf(lrelu(l4.y + r4.y) - m4.y) * zi.y,
                         expf(lrelu(l4.z + r4.z) - m4.z) * zi.z,
                         expf(lrelu(l4.w + r4.w) - m4.w) * zi.w);
}

// ---------------------------------------------------------------------------
extern "C" void kernel_launch(void* const* d_in, const int* in_sizes, int n_in,
                              void* d_out, int out_size, void* d_ws, size_t ws_size,
                              hipStream_t stream)
{
    const int*   src = (const int*)d_in[0];
    const int*   dst = (const int*)d_in[1];
    const float* hc  = (const float*)d_in[2];
    const float* ht  = (const float*)d_in[3];
    const float* hr  = (const float*)d_in[4];
    const float* Wc  = (const float*)d_in[5];
    const float* Wt  = (const float*)d_in[6];
    const float* Wr  = (const float*)d_in[7];
    const float* fw  = (const float*)d_in[8];
    const float* fb  = (const float*)d_in[9];
    const float* W0  = (const float*)d_in[10];
    const float* al0 = (const float*)d_in[11];
    const float* ar0 = (const float*)d_in[12];
    const float* b0  = (const float*)d_in[13];
    const float* W1  = (const float*)d_in[14];
    const float* al1 = (const float*)d_in[15];
    const float* ar1 = (const float*)d_in[16];
    const float* b1  = (const float*)d_in[17];

    // workspace layout (bytes); round-2 proved ws_size >= 69,200,064
    char* ws = (char*)d_ws;
    unsigned short* h0b   = (unsigned short*)(ws);               // N*64  bf16 :  6,400,000
    unsigned short* h1b   = (unsigned short*)(ws + 6400000);     // N*256 bf16 : 25,600,000 (head-minor)
    unsigned short* featb = (unsigned short*)(ws + 32000000);    // N*256 bf16 : 25,600,000 (head-minor)
    float* el    = (float*)(ws + 57600000);                      //    800,000
    float* er    = (float*)(ws + 58400000);                      //    800,000
    int*   cnt   = (int*)  (ws + 59200000);                      //    200,000
    int*   offs  = (int*)  (ws + 59400000);                      //    200,064 (padded)
    int*   esort = (int*)  (ws + 59600128);                      //  3,200,000
    unsigned short* wpc = (unsigned short*)(ws + 62800128);      //  4*16KB =  65,536
    unsigned short* wpt = (unsigned short*)(ws + 62865664);      // 16*16KB = 262,144
    unsigned short* wpr = (unsigned short*)(ws + 63127808);      // 16*16KB = 262,144
    unsigned short* wp0 = (unsigned short*)(ws + 63389952);      //  2*16KB =  32,768
    unsigned short* wp1 = (unsigned short*)(ws + 63422720);      //  8*16KB = 131,072
    float4* mbuf = (float4*)(ws + 63553792);                     //    800,000
    float4* zbuf = (float4*)(ws + 64353792);                     //    800,000
    int* srcsort = (int*)  (ws + 65153792);                      //  3,200,000
    if (ws_size < 68353792ull) return;                           // end of layout

    float* outh = (float*)d_out;                       // N*256 final h
    float4* atto = (float4*)(outh + (size_t)NN * 256); // E*4 att region

    // A-pack overlays (live only during fusion)
    unsigned short* apt = (unsigned short*)d_out;                     // 51,200,000
    unsigned short* apc = (unsigned short*)((char*)d_out + 51200000); // 12,800,000
    unsigned short* apr = (unsigned short*)(ws + 6400000);            // 51,200,000

    // weight packing
    pack_w_fusion<<<(4 * 16 * 64 + 255) / 256, 256, 0, stream>>>(Wc, wpc, 129, 4);
    pack_w_fusion<<<(16 * 16 * 64 + 255) / 256, 256, 0, stream>>>(Wt, wpt, 513, 16);
    pack_w_fusion<<<(16 * 16 * 64 + 255) / 256, 256, 0, stream>>>(Wr, wpr, 513, 16);
    pack_w_gemm<0><<<(2 * 16 * 64 + 255) / 256, 256, 0, stream>>>(W0, wp0, 64, 256);
    pack_w_gemm<1><<<(8 * 16 * 64 + 255) / 256, 256, 0, stream>>>(W1, wp1, 256, 256);

    // F1: feature packs (f32 -> bf16 A-fragment order), 128-k tiles
    pack_a_tile<129, 4><<<NG * 1, 256, 0, stream>>>(hc, apc);
    pack_a_tile<513, 16><<<NG * 4, 256, 0, stream>>>(ht, apt);
    pack_a_tile<513, 16><<<NG * 4, 256, 0, stream>>>(hr, apr);

    // F2: trilinear fusion (rank-split, R9-exact structure)
    fusion_mfma<<<NG, 256, 0, stream>>>(apc, apt, apr, wpc, wpt, wpr,
                                        Wc, Wt, Wr, fw, fb, h0b);

    // CSR by dst
    hipMemsetAsync(cnt, 0, NN * sizeof(int), stream);
    hist_kernel<<<(EE + 255) / 256, 256, 0, stream>>>(dst, cnt);
    scan_kernel<<<1, 1024, 0, stream>>>(cnt, offs);
    hipMemsetAsync(cnt, 0, NN * sizeof(int), stream);
    scatter_kernel<<<(EE + 255) / 256, 256, 0, stream>>>(dst, offs, cnt, esort);

    // GAT layer 0: feat + el/er fused; output only bf16 h1b (head-minor)
    gemm_reg<64><<<NG, 256, 0, stream>>>(h0b, wp0, al0, ar0, featb, el, er);
    edge_prep<<<(EE + 255) / 256, 256, 0, stream>>>(esort, src, dst, el, er, atto, srcsort);
    gat_agg<0, 0, 1, 0><<<(NN * 64 + 255) / 256, 256, 0, stream>>>(
        srcsort, offs, featb, atto, nullptr, b0, nullptr, h1b, nullptr, nullptr);

    // GAT layer 1: feat + el/er fused; residual from bf16 h1b; f32 out
    gemm_reg<256><<<NG, 256, 0, stream>>>(h1b, wp1, al1, ar1, featb, el, er);
    edge_prep<<<(EE + 255) / 256, 256, 0, stream>>>(esort, src, dst, el, er, atto, srcsort);
    gat_agg<1, 1, 0, 1><<<(NN * 64 + 255) / 256, 256, 0, stream>>>(
        srcsort, offs, featb, atto, h1b, b1, outh, nullptr, mbuf, zbuf);
    att_final<<<(EE + 255) / 256, 256, 0, stream>>>(src, dst, el, er, mbuf, zbuf, atto);
}

// Round 15
// 571.788 us; speedup vs baseline: 1.1148x; 1.0116x over previous
//
#include <hip/hip_runtime.h>
#include <math.h>

#define NN 50000
#define EE 800000
#define NEG 0.2f
#define NG (NN / 16)   // 3125 node groups

using f32x4  = __attribute__((ext_vector_type(4))) float;
using bf16x8 = __attribute__((ext_vector_type(8))) short;

__device__ __forceinline__ float lrelu(float x){ return x > 0.f ? x : NEG*x; }

__device__ __forceinline__ unsigned short f2b(float f){
    unsigned int u = __float_as_uint(f);
    return (unsigned short)((u + 0x7FFFu + ((u >> 16) & 1u)) >> 16);  // RNE
}
__device__ __forceinline__ float b2f(unsigned short h){
    return __uint_as_float(((unsigned int)h) << 16);
}
__device__ __forceinline__ void gld_lds16(const void* g, void* l){
    __builtin_amdgcn_global_load_lds(
        (const __attribute__((address_space(1))) unsigned int*)g,
        (__attribute__((address_space(3))) unsigned int*)l, 16, 0, 0);
}

// ---------------------------------------------------------------------------
// Weight packers (fragment-order bf16).
// Fusion: chunk = ct*4 + r. k < K-1 only (ones-row handled via acc init).
// ---------------------------------------------------------------------------
__global__ void pack_w_fusion(const float* __restrict__ W, unsigned short* __restrict__ out,
                              int K, int NKC)
{
    int u = blockIdx.x * blockDim.x + threadIdx.x;
    if (u >= NKC * 16 * 64) return;
    int l = u & 63, chunk = (u >> 6) & 15, kc = u >> 10;
    int ct = chunk >> 2, r = chunk & 3;
    int c = ct * 16 + (l & 15);
    int kb = kc * 32 + (l >> 4) * 8;
    bf16x8 v;
#pragma unroll
    for (int j = 0; j < 8; ++j)
        v[j] = (short)f2b(W[((size_t)r * K + kb + j) * 64 + c]);
    *(bf16x8*)(out + (size_t)u * 8) = v;
}

// GEMM weights: chunk = ct (C/16 chunks per kc); K multiple of 32.
// PERM=1: A rows are stored head-minor (k_store = d*4+h <-> k_orig = h*64+d).
template<int PERM>
__global__ void pack_w_gemm(const float* __restrict__ W, unsigned short* __restrict__ out,
                            int K, int C)
{
    int NCH = C / 16;
    int total = (K / 32) * NCH * 64;
    int u = blockIdx.x * blockDim.x + threadIdx.x;
    if (u >= total) return;
    int l = u & 63, ch = (u >> 6) % NCH, kc = u / (64 * NCH);
    int c = ch * 16 + (l & 15);
    int kb = kc * 32 + (l >> 4) * 8;
    bf16x8 v;
#pragma unroll
    for (int j = 0; j < 8; ++j) {
        int k = kb + j;
        int ko = PERM ? ((k & 3) * 64 + (k >> 2)) : k;
        v[j] = (short)f2b(W[(size_t)ko * C + c]);
    }
    *(bf16x8*)(out + (size_t)u * 8) = v;
}

// ---------------------------------------------------------------------------
// pack_a_tile: f32 features -> bf16 A-fragment order [group][kc][lane][8]
// Tile = 16 nodes x 128 k (4 kc chunks). LDS 8.3KB -> high occupancy.
// ---------------------------------------------------------------------------
template<int KT, int NKC>
__global__ __launch_bounds__(256) void pack_a_tile(
    const float* __restrict__ F, unsigned short* __restrict__ out)
{
    constexpr int TILES = NKC / 4;           // 4 for K=513, 1 for K=129
    __shared__ float sf[16][130];
    const int tid = threadIdx.x;
    const int g = blockIdx.x / TILES, t = blockIdx.x % TILES;
    const int nb = g * 16, k0 = t * 128;

#pragma unroll
    for (int i = 0; i < 8; ++i) {
        int idx = tid + i * 256;             // 0..2047
        int row = idx >> 7, k = idx & 127;
        sf[row][k] = F[(size_t)(nb + row) * KT + k0 + k];
    }
    __syncthreads();
    {
        int kcl = tid >> 6, l = tid & 63;
        int row = l & 15, kb = kcl * 32 + (l >> 4) * 8;
        bf16x8 o;
#pragma unroll
        for (int j = 0; j < 8; ++j) o[j] = (short)f2b(sf[row][kb + j]);
        *(bf16x8*)(out + ((size_t)(g * NKC + t * 4 + kcl) * 64 + l) * 8) = o;
    }
}

// ---------------------------------------------------------------------------
// Fusion, rank-split + LDS-staged A: the 36 A-chunks (36KB) of the group are
// staged ONCE via global_load_lds (no VGPR dests -> all 36 stay in flight;
// latency paid once per block, not per chunk per wave). All 4 rank-waves
// read the same LDS A-frags; B-frags stay global (L1/L2-hot).
// ---------------------------------------------------------------------------
template<int NKC>
__device__ __forceinline__ void fusion_pass_lds(
    const unsigned short* __restrict__ ldsA, int cbase,
    const unsigned short* __restrict__ wp,
    const float* __restrict__ W, int K, int w, int l, f32x4 (&acc)[4])
{
    const int c_lo = l & 15;
#pragma unroll
    for (int ct = 0; ct < 4; ++ct) {
        float wi = W[((size_t)w * K + (K - 1)) * 64 + ct * 16 + c_lo];
        acc[ct] = f32x4{wi, wi, wi, wi};
    }
#pragma unroll
    for (int kc = 0; kc < NKC; ++kc) {
        bf16x8 af = *(const bf16x8*)(ldsA + (cbase + kc) * 512 + l * 8);
        const unsigned short* wk = wp + (size_t)kc * 8192 + w * 512 + l * 8;
#pragma unroll
        for (int ct = 0; ct < 4; ++ct) {
            bf16x8 bf = *(const bf16x8*)(wk + ct * 2048);   // chunk = ct*4 + w
            acc[ct] = __builtin_amdgcn_mfma_f32_16x16x32_bf16(af, bf, acc[ct], 0, 0, 0);
        }
    }
}

__global__ __launch_bounds__(256) void fusion_mfma(
    const unsigned short* __restrict__ apc, const unsigned short* __restrict__ apt,
    const unsigned short* __restrict__ apr,
    const unsigned short* __restrict__ wpc, const unsigned short* __restrict__ wpt,
    const unsigned short* __restrict__ wpr,
    const float* __restrict__ Wc, const float* __restrict__ Wt, const float* __restrict__ Wr,
    const float* __restrict__ fw, const float* __restrict__ fb,
    unsigned short* __restrict__ h0b)
{
    __shared__ __align__(16) char smem[36864];      // 36 chunks x 1KB
    unsigned short* ldsA = (unsigned short*)smem;
    float* ldsx = (float*)smem;                     // aliased exchange (16KB)
    const int w = threadIdx.x >> 6, l = threadIdx.x & 63;
    const int G = blockIdx.x;

    // stage all 36 A-chunks: wave w issues chunks [9w, 9w+9)
#pragma unroll
    for (int j = 0; j < 9; ++j) {
        int cid = w * 9 + j;
        const unsigned short* s;
        if (cid < 4)       s = apc + ((size_t)G * 4  + cid) * 512;
        else if (cid < 20) s = apt + ((size_t)G * 16 + (cid - 4)) * 512;
        else               s = apr + ((size_t)G * 16 + (cid - 20)) * 512;
        gld_lds16(s + l * 8, ldsA + cid * 512);
    }
    __syncthreads();   // drains vmcnt: latency paid once per block

    f32x4 prod[4], acc[4];
    fusion_pass_lds<4>(ldsA, 0, wpc, Wc, 129, w, l, acc);
#pragma unroll
    for (int ct = 0; ct < 4; ++ct) prod[ct] = acc[ct];
    fusion_pass_lds<16>(ldsA, 4, wpt, Wt, 513, w, l, acc);
#pragma unroll
    for (int ct = 0; ct < 4; ++ct) prod[ct] *= acc[ct];
    fusion_pass_lds<16>(ldsA, 20, wpr, Wr, 513, w, l, acc);
    const float fww = fw[w];
#pragma unroll
    for (int ct = 0; ct < 4; ++ct) prod[ct] = prod[ct] * acc[ct] * fww;

    __syncthreads();   // all waves done reading A before exchange overwrites
#pragma unroll
    for (int ct = 0; ct < 4; ++ct)
        *(f32x4*)&ldsx[((w * 4 + ct) * 64 + l) * 4] = prod[ct];
    __syncthreads();

    // wave w sums the 4 ranks for col-tile ct = w
    f32x4 s = *(const f32x4*)&ldsx[((0 * 4 + w) * 64 + l) * 4];
#pragma unroll
    for (int r = 1; r < 4; ++r)
        s += *(const f32x4*)&ldsx[((r * 4 + w) * 64 + l) * 4];

    const int c = w * 16 + (l & 15);
    const float fbc = fb[c];
#pragma unroll
    for (int q = 0; q < 4; ++q) {
        int n = G * 16 + (l >> 4) * 4 + q;
        float v = s[q] + fbc;
        v = v > 0.f ? v : expm1f(v);
        h0b[(size_t)n * 64 + c] = f2b(v);
    }
}

// ---------------------------------------------------------------------------
// feat GEMM with FUSED el/er epilogue. Wave w == head w: its acc covers all
// 64 features of head w for the block's 16 nodes -> el/er via 4 fma/lane +
// 16-lane shuffle reduce. Output feat HEAD-MINOR: featb[n][d*4+h].
// ---------------------------------------------------------------------------
template<int K>
__global__ __launch_bounds__(256) void gemm_reg(
    const unsigned short* __restrict__ Ab, const unsigned short* __restrict__ wp,
    const float* __restrict__ al, const float* __restrict__ ar,
    unsigned short* __restrict__ featb,
    float* __restrict__ el, float* __restrict__ er)
{
    constexpr int NKC = K / 32;
    const int w = threadIdx.x >> 6, l = threadIdx.x & 63;
    const int nb = blockIdx.x * 16;

    f32x4 acc[4];
#pragma unroll
    for (int i = 0; i < 4; ++i) acc[i] = f32x4{0.f, 0.f, 0.f, 0.f};

    const unsigned short* abase = Ab + (size_t)(nb + (l & 15)) * K + (l >> 4) * 8;
    bf16x8 afs[NKC];
#pragma unroll
    for (int kc = 0; kc < NKC; ++kc)
        afs[kc] = *(const bf16x8*)(abase + kc * 32);

    bf16x8 bcur[4];
    {
        const unsigned short* wk = wp + (size_t)(0 * 16 + w * 4) * 512 + l * 8;
#pragma unroll
        for (int i = 0; i < 4; ++i) bcur[i] = *(const bf16x8*)(wk + i * 512);
    }
#pragma unroll
    for (int kc = 0; kc < NKC; ++kc) {
        bf16x8 bnxt[4];
        if (kc + 1 < NKC) {
            const unsigned short* wk = wp + ((size_t)(kc + 1) * 16 + w * 4) * 512 + l * 8;
#pragma unroll
            for (int i = 0; i < 4; ++i) bnxt[i] = *(const bf16x8*)(wk + i * 512);
        }
#pragma unroll
        for (int i = 0; i < 4; ++i)
            acc[i] = __builtin_amdgcn_mfma_f32_16x16x32_bf16(afs[kc], bcur[i], acc[i], 0, 0, 0);
        if (kc + 1 < NKC) {
#pragma unroll
            for (int i = 0; i < 4; ++i) bcur[i] = bnxt[i];
        }
    }

    // feat store (head-minor)
#pragma unroll
    for (int i = 0; i < 4; ++i) {
        int c = (w * 4 + i) * 16 + (l & 15);
        int dm = (c & 63) * 4 + (c >> 6);
#pragma unroll
        for (int q = 0; q < 4; ++q) {
            int n = nb + (l >> 4) * 4 + q;
            featb[(size_t)n * 256 + dm] = f2b(acc[i][q]);
        }
    }

    // fused el/er for head h = w
    float pel[4] = {0.f, 0.f, 0.f, 0.f};
    float per_[4] = {0.f, 0.f, 0.f, 0.f};
#pragma unroll
    for (int i = 0; i < 4; ++i) {
        int d = i * 16 + (l & 15);
        float av = al[w * 64 + d];
        float rv = ar[w * 64 + d];
#pragma unroll
        for (int q = 0; q < 4; ++q) {
            pel[q] += acc[i][q] * av;
            per_[q] += acc[i][q] * rv;
        }
    }
#pragma unroll
    for (int off = 1; off <= 8; off <<= 1) {
#pragma unroll
        for (int q = 0; q < 4; ++q) {
            pel[q] += __shfl_xor(pel[q], off);
            per_[q] += __shfl_xor(per_[q], off);
        }
    }
    int qsel = l & 15;
    if (qsel < 4) {
        float ev = qsel == 0 ? pel[0] : qsel == 1 ? pel[1] : qsel == 2 ? pel[2] : pel[3];
        float rv = qsel == 0 ? per_[0] : qsel == 1 ? per_[1] : qsel == 2 ? per_[2] : per_[3];
        int n = nb + (l >> 4) * 4 + qsel;
        el[(size_t)n * 4 + w] = ev;
        er[(size_t)n * 4 + w] = rv;
    }
}

// ---------------------------------------------------------------------------
// CSR build
// ---------------------------------------------------------------------------
__global__ void hist_kernel(const int* __restrict__ dst, int* __restrict__ cnt)
{
    int e = blockIdx.x * blockDim.x + threadIdx.x;
    if (e < EE) atomicAdd(&cnt[dst[e]], 1);
}

__global__ __launch_bounds__(1024) void scan_kernel(const int* __restrict__ cnt, int* __restrict__ offs)
{
    __shared__ int tmp[1024];
    const int t = threadIdx.x;
    const int C = (NN + 1023) / 1024;
    int lo = t * C, hi = min(lo + C, NN);
    int s = 0;
    for (int i = lo; i < hi; ++i) s += cnt[i];
    tmp[t] = s;
    __syncthreads();
    for (int off = 1; off < 1024; off <<= 1) {
        int v = (t >= off) ? tmp[t - off] : 0;
        __syncthreads();
        tmp[t] += v;
        __syncthreads();
    }
    int run = (t == 0) ? 0 : tmp[t - 1];
    for (int i = lo; i < hi; ++i) { offs[i] = run; run += cnt[i]; }
    if (t == 1023) offs[NN] = tmp[1023];
}

__global__ void scatter_kernel(const int* __restrict__ dst, const int* __restrict__ offs,
                               int* __restrict__ cur, int* __restrict__ esort)
{
    int e = blockIdx.x * blockDim.x + threadIdx.x;
    if (e < EE) {
        int d = dst[e];
        int p = offs[d] + atomicAdd(&cur[d], 1);
        esort[p] = e;
    }
}

// ---------------------------------------------------------------------------
// edge_prep: CSR-ordered logits + CSR-ordered src index.
// ---------------------------------------------------------------------------
__global__ void edge_prep(const int* __restrict__ esort, const int* __restrict__ src,
                          const int* __restrict__ dst,
                          const float* __restrict__ el, const float* __restrict__ er,
                          float4* __restrict__ eesort, int* __restrict__ srcsort)
{
    int p = blockIdx.x * blockDim.x + threadIdx.x;
    if (p >= EE) return;
    int e = esort[p];
    int s = src[e], d = dst[e];
    srcsort[p] = s;
    float4 l4 = *(const float4*)(el + (size_t)s * 4);
    float4 r4 = *(const float4*)(er + (size_t)d * 4);
    eesort[p] = make_float4(lrelu(l4.x + r4.x), lrelu(l4.y + r4.y),
                            lrelu(l4.z + r4.z), lrelu(l4.w + r4.w));
}

// ---------------------------------------------------------------------------
// Per-dst softmax + aggregation. One wave per node.
// Pass A: strided max. Pass B: strided exp writeback + z-sum.
// Pass C: serial edges x4-unrolled, weights ready-made, 1/z deferred.
// ---------------------------------------------------------------------------
template <int RESID, int WMZ, int WB16, int WF32>
__global__ __launch_bounds__(256) void gat_agg(
    const int* __restrict__ srcsort, const int* __restrict__ offs,
    const unsigned short* __restrict__ featb, float4* __restrict__ eesort,
    const unsigned short* __restrict__ residb, const float* __restrict__ bias,
    float* __restrict__ out, unsigned short* __restrict__ outb,
    float4* __restrict__ mbuf, float4* __restrict__ zbuf)
{
    int n = (int)((blockIdx.x * (size_t)blockDim.x + threadIdx.x) >> 6);
    int lane = threadIdx.x & 63;
    if (n >= NN) return;
    int s0 = offs[n], s1 = offs[n + 1];

    float m0 = -1e30f, m1 = -1e30f, m2 = -1e30f, m3 = -1e30f;
    for (int p = s0 + lane; p < s1; p += 64) {
        float4 v = eesort[p];
        m0 = fmaxf(m0, v.x); m1 = fmaxf(m1, v.y);
        m2 = fmaxf(m2, v.z); m3 = fmaxf(m3, v.w);
    }
#pragma unroll
    for (int off = 32; off; off >>= 1) {
        m0 = fmaxf(m0, __shfl_xor(m0, off));
        m1 = fmaxf(m1, __shfl_xor(m1, off));
        m2 = fmaxf(m2, __shfl_xor(m2, off));
        m3 = fmaxf(m3, __shfl_xor(m3, off));
    }

    float z0 = 0.f, z1 = 0.f, z2 = 0.f, z3 = 0.f;
    for (int p = s0 + lane; p < s1; p += 64) {
        float4 v = eesort[p];
        v.x = expf(v.x - m0); v.y = expf(v.y - m1);
        v.z = expf(v.z - m2); v.w = expf(v.w - m3);
        eesort[p] = v;
        z0 += v.x; z1 += v.y; z2 += v.z; z3 += v.w;
    }
    __threadfence_block();   // make lane-strided writebacks visible wave-wide
#pragma unroll
    for (int off = 32; off; off >>= 1) {
        z0 += __shfl_xor(z0, off);
        z1 += __shfl_xor(z1, off);
        z2 += __shfl_xor(z2, off);
        z3 += __shfl_xor(z3, off);
    }
    float i0 = z0 > 0.f ? 1.f / z0 : 0.f;
    float i1 = z1 > 0.f ? 1.f / z1 : 0.f;
    float i2 = z2 > 0.f ? 1.f / z2 : 0.f;
    float i3 = z3 > 0.f ? 1.f / z3 : 0.f;
    if (WMZ && lane == 0) {
        mbuf[n] = make_float4(m0, m1, m2, m3);
        zbuf[n] = make_float4(i0, i1, i2, i3);
    }

    float a0 = 0.f, a1 = 0.f, a2 = 0.f, a3 = 0.f;
    float c0 = 0.f, c1 = 0.f, c2 = 0.f, c3 = 0.f;
    int p = s0;
    for (; p + 3 < s1; p += 4) {
        float4 wA = eesort[p],     wB = eesort[p + 1];
        float4 wC = eesort[p + 2], wD = eesort[p + 3];
        int sA = srcsort[p],     sB = srcsort[p + 1];
        int sC = srcsort[p + 2], sD = srcsort[p + 3];
        ushort4 fA = *(const ushort4*)(featb + (size_t)sA * 256 + lane * 4);
        ushort4 fB = *(const ushort4*)(featb + (size_t)sB * 256 + lane * 4);
        ushort4 fC = *(const ushort4*)(featb + (size_t)sC * 256 + lane * 4);
        ushort4 fD = *(const ushort4*)(featb + (size_t)sD * 256 + lane * 4);
        a0 += wA.x * b2f(fA.x);  c0 += wB.x * b2f(fB.x);
        a1 += wA.y * b2f(fA.y);  c1 += wB.y * b2f(fB.y);
        a2 += wA.z * b2f(fA.z);  c2 += wB.z * b2f(fB.z);
        a3 += wA.w * b2f(fA.w);  c3 += wB.w * b2f(fB.w);
        a0 += wC.x * b2f(fC.x);  c0 += wD.x * b2f(fD.x);
        a1 += wC.y * b2f(fC.y);  c1 += wD.y * b2f(fD.y);
        a2 += wC.z * b2f(fC.z);  c2 += wD.z * b2f(fD.z);
        a3 += wC.w * b2f(fC.w);  c3 += wD.w * b2f(fD.w);
    }
    for (; p < s1; ++p) {
        float4 wA = eesort[p];
        int sA = srcsort[p];
        ushort4 fA = *(const ushort4*)(featb + (size_t)sA * 256 + lane * 4);
        a0 += wA.x * b2f(fA.x);
        a1 += wA.y * b2f(fA.y);
        a2 += wA.z * b2f(fA.z);
        a3 += wA.w * b2f(fA.w);
    }
    a0 += c0; a1 += c1; a2 += c2; a3 += c3;

    float o0 = a0 * i0 + bias[lane];
    float o1 = a1 * i1 + bias[64 + lane];
    float o2 = a2 * i2 + bias[128 + lane];
    float o3 = a3 * i3 + bias[192 + lane];
    if (RESID) {
        ushort4 rp = *(const ushort4*)(residb + (size_t)n * 256 + lane * 4);
        o0 += b2f(rp.x); o1 += b2f(rp.y); o2 += b2f(rp.z); o3 += b2f(rp.w);
    }
    if (WF32) {
        float* op = out + (size_t)n * 256;
        op[lane] = o0;
        op[64 + lane] = o1;
        op[128 + lane] = o2;
        op[192 + lane] = o3;
    }
    if (WB16) {
        ushort4 ob;
        ob.x = f2b(o0); ob.y = f2b(o1); ob.z = f2b(o2); ob.w = f2b(o3);
        *(ushort4*)(outb + (size_t)n * 256 + lane * 4) = ob;
    }
}

// ---------------------------------------------------------------------------
// att_final: att[e] = exp(lrelu(el[src]+er[dst]) - m[dst]) * i[dst]
// ---------------------------------------------------------------------------
__global__ void att_final(const int* __restrict__ src, const int* __restrict__ dst,
                          const float* __restrict__ el, const float* __restrict__ er,
                          const float4* __restrict__ mbuf, const float4* __restrict__ zbuf,
                          float4* __restrict__ att)
{
    int e = blockIdx.x * blockDim.x + threadIdx.x;
    if (e >= EE) return;
    int s = src[e], d = dst[e];
    float4 l4 = *(const float4*)(el + (size_t)s * 4);
    float4 r4 = *(const float4*)(er + (size_t)d * 4);
    float4 m4 = mbuf[d], zi = zbuf[d];
    att[e] = make_float4(expf(lrelu(l4.x + r4.x) - m4.x) * zi.x,
                         expf(lrelu(l4.y + r4.y) - m4.y) * zi.y,
                         expf(lrelu(l4.z + r4.z) - m4.z) * zi.z,
                         expf(lrelu(l4.w + r4.w) - m4.w) * zi.w);
}

// ---------------------------------------------------------------------------
extern "C" void kernel_launch(void* const* d_in, const int* in_sizes, int n_in,
                              void* d_out, int out_size, void* d_ws, size_t ws_size,
                              hipStream_t stream)
{
    const int*   src = (const int*)d_in[0];
    const int*   dst = (const int*)d_in[1];
    const float* hc  = (const float*)d_in[2];
    const float* ht  = (const float*)d_in[3];
    const float* hr  = (const float*)d_in[4];
    const float* Wc  = (const float*)d_in[5];
    const float* Wt  = (const float*)d_in[6];
    const float* Wr  = (const float*)d_in[7];
    const float* fw  = (const float*)d_in[8];
    const float* fb  = (const float*)d_in[9];
    const float* W0  = (const float*)d_in[10];
    const float* al0 = (const float*)d_in[11];
    const float* ar0 = (const float*)d_in[12];
    const float* b0  = (const float*)d_in[13];
    const float* W1  = (const float*)d_in[14];
    const float* al1 = (const float*)d_in[15];
    const float* ar1 = (const float*)d_in[16];
    const float* b1  = (const float*)d_in[17];

    // workspace layout (bytes); round-2 proved ws_size >= 69,200,064
    char* ws = (char*)d_ws;
    unsigned short* h0b   = (unsigned short*)(ws);               // N*64  bf16 :  6,400,000
    unsigned short* h1b   = (unsigned short*)(ws + 6400000);     // N*256 bf16 : 25,600,000 (head-minor)
    unsigned short* featb = (unsigned short*)(ws + 32000000);    // N*256 bf16 : 25,600,000 (head-minor)
    float* el    = (float*)(ws + 57600000);                      //    800,000
    float* er    = (float*)(ws + 58400000);                      //    800,000
    int*   cnt   = (int*)  (ws + 59200000);                      //    200,000
    int*   offs  = (int*)  (ws + 59400000);                      //    200,064 (padded)
    int*   esort = (int*)  (ws + 59600128);                      //  3,200,000
    unsigned short* wpc = (unsigned short*)(ws + 62800128);      //  4*16KB =  65,536
    unsigned short* wpt = (unsigned short*)(ws + 62865664);      // 16*16KB = 262,144
    unsigned short* wpr = (unsigned short*)(ws + 63127808);      // 16*16KB = 262,144
    unsigned short* wp0 = (unsigned short*)(ws + 63389952);      //  2*16KB =  32,768
    unsigned short* wp1 = (unsigned short*)(ws + 63422720);      //  8*16KB = 131,072
    float4* mbuf = (float4*)(ws + 63553792);                     //    800,000
    float4* zbuf = (float4*)(ws + 64353792);                     //    800,000
    int* srcsort = (int*)  (ws + 65153792);                      //  3,200,000
    if (ws_size < 68353792ull) return;                           // end of layout

    float* outh = (float*)d_out;                       // N*256 final h
    float4* atto = (float4*)(outh + (size_t)NN * 256); // E*4 att region

    // A-pack overlays (live only during fusion)
    unsigned short* apt = (unsigned short*)d_out;                     // 51,200,000
    unsigned short* apc = (unsigned short*)((char*)d_out + 51200000); // 12,800,000
    unsigned short* apr = (unsigned short*)(ws + 6400000);            // 51,200,000

    // weight packing
    pack_w_fusion<<<(4 * 16 * 64 + 255) / 256, 256, 0, stream>>>(Wc, wpc, 129, 4);
    pack_w_fusion<<<(16 * 16 * 64 + 255) / 256, 256, 0, stream>>>(Wt, wpt, 513, 16);
    pack_w_fusion<<<(16 * 16 * 64 + 255) / 256, 256, 0, stream>>>(Wr, wpr, 513, 16);
    pack_w_gemm<0><<<(2 * 16 * 64 + 255) / 256, 256, 0, stream>>>(W0, wp0, 64, 256);
    pack_w_gemm<1><<<(8 * 16 * 64 + 255) / 256, 256, 0, stream>>>(W1, wp1, 256, 256);

    // F1: feature packs (f32 -> bf16 A-fragment order), 128-k tiles
    pack_a_tile<129, 4><<<NG * 1, 256, 0, stream>>>(hc, apc);
    pack_a_tile<513, 16><<<NG * 4, 256, 0, stream>>>(ht, apt);
    pack_a_tile<513, 16><<<NG * 4, 256, 0, stream>>>(hr, apr);

    // F2: trilinear fusion (rank-split, LDS-staged A)
    fusion_mfma<<<NG, 256, 0, stream>>>(apc, apt, apr, wpc, wpt, wpr,
                                        Wc, Wt, Wr, fw, fb, h0b);

    // CSR by dst
    hipMemsetAsync(cnt, 0, NN * sizeof(int), stream);
    hist_kernel<<<(EE + 255) / 256, 256, 0, stream>>>(dst, cnt);
    scan_kernel<<<1, 1024, 0, stream>>>(cnt, offs);
    hipMemsetAsync(cnt, 0, NN * sizeof(int), stream);
    scatter_kernel<<<(EE + 255) / 256, 256, 0, stream>>>(dst, offs, cnt, esort);

    // GAT layer 0: feat + el/er fused; output only bf16 h1b (head-minor)
    gemm_reg<64><<<NG, 256, 0, stream>>>(h0b, wp0, al0, ar0, featb, el, er);
    edge_prep<<<(EE + 255) / 256, 256, 0, stream>>>(esort, src, dst, el, er, atto, srcsort);
    gat_agg<0, 0, 1, 0><<<(NN * 64 + 255) / 256, 256, 0, stream>>>(
        srcsort, offs, featb, atto, nullptr, b0, nullptr, h1b, nullptr, nullptr);

    // GAT layer 1: feat + el/er fused; residual from bf16 h1b; f32 out
    gemm_reg<256><<<NG, 256, 0, stream>>>(h1b, wp1, al1, ar1, featb, el, er);
    edge_prep<<<(EE + 255) / 256, 256, 0, stream>>>(esort, src, dst, el, er, atto, srcsort);
    gat_agg<1, 1, 0, 1><<<(NN * 64 + 255) / 256, 256, 0, stream>>>(
        srcsort, offs, featb, atto, h1b, b1, outh, nullptr, mbuf, zbuf);
    att_final<<<(EE + 255) / 256, 256, 0, stream>>>(src, dst, el, er, mbuf, zbuf, atto);
}

// Round 16
// 548.910 us; speedup vs baseline: 1.1612x; 1.0417x over previous
//
#include <hip/hip_runtime.h>
#include <math.h>

#define NN 50000
#define EE 800000
#define NEG 0.2f
#define NG (NN / 16)   // 3125 node groups

using f32x4  = __attribute__((ext_vector_type(4))) float;
using bf16x8 = __attribute__((ext_vector_type(8))) short;

__device__ __forceinline__ float lrelu(float x){ return x > 0.f ? x : NEG*x; }

__device__ __forceinline__ unsigned short f2b(float f){
    unsigned int u = __float_as_uint(f);
    return (unsigned short)((u + 0x7FFFu + ((u >> 16) & 1u)) >> 16);  // RNE
}
__device__ __forceinline__ float b2f(unsigned short h){
    return __uint_as_float(((unsigned int)h) << 16);
}
__device__ __forceinline__ void gld_lds16(const void* g, void* l){
    __builtin_amdgcn_global_load_lds(
        (const __attribute__((address_space(1))) unsigned int*)g,
        (__attribute__((address_space(3))) unsigned int*)l, 16, 0, 0);
}

// ---------------------------------------------------------------------------
// Weight packers (fragment-order bf16).
// ---------------------------------------------------------------------------
__global__ void pack_w_fusion(const float* __restrict__ W, unsigned short* __restrict__ out,
                              int K, int NKC)
{
    int u = blockIdx.x * blockDim.x + threadIdx.x;
    if (u >= NKC * 16 * 64) return;
    int l = u & 63, chunk = (u >> 6) & 15, kc = u >> 10;
    int ct = chunk >> 2, r = chunk & 3;
    int c = ct * 16 + (l & 15);
    int kb = kc * 32 + (l >> 4) * 8;
    bf16x8 v;
#pragma unroll
    for (int j = 0; j < 8; ++j)
        v[j] = (short)f2b(W[((size_t)r * K + kb + j) * 64 + c]);
    *(bf16x8*)(out + (size_t)u * 8) = v;
}

template<int PERM>
__global__ void pack_w_gemm(const float* __restrict__ W, unsigned short* __restrict__ out,
                            int K, int C)
{
    int NCH = C / 16;
    int total = (K / 32) * NCH * 64;
    int u = blockIdx.x * blockDim.x + threadIdx.x;
    if (u >= total) return;
    int l = u & 63, ch = (u >> 6) % NCH, kc = u / (64 * NCH);
    int c = ch * 16 + (l & 15);
    int kb = kc * 32 + (l >> 4) * 8;
    bf16x8 v;
#pragma unroll
    for (int j = 0; j < 8; ++j) {
        int k = kb + j;
        int ko = PERM ? ((k & 3) * 64 + (k >> 2)) : k;
        v[j] = (short)f2b(W[(size_t)ko * C + c]);
    }
    *(bf16x8*)(out + (size_t)u * 8) = v;
}

// ---------------------------------------------------------------------------
// pack_a_tile: f32 features -> bf16 A-fragment order [group][kc][lane][8]
// ---------------------------------------------------------------------------
template<int KT, int NKC>
__global__ __launch_bounds__(256) void pack_a_tile(
    const float* __restrict__ F, unsigned short* __restrict__ out)
{
    constexpr int TILES = NKC / 4;
    __shared__ float sf[16][130];
    const int tid = threadIdx.x;
    const int g = blockIdx.x / TILES, t = blockIdx.x % TILES;
    const int nb = g * 16, k0 = t * 128;

#pragma unroll
    for (int i = 0; i < 8; ++i) {
        int idx = tid + i * 256;
        int row = idx >> 7, k = idx & 127;
        sf[row][k] = F[(size_t)(nb + row) * KT + k0 + k];
    }
    __syncthreads();
    {
        int kcl = tid >> 6, l = tid & 63;
        int row = l & 15, kb = kcl * 32 + (l >> 4) * 8;
        bf16x8 o;
#pragma unroll
        for (int j = 0; j < 8; ++j) o[j] = (short)f2b(sf[row][kb + j]);
        *(bf16x8*)(out + ((size_t)(g * NKC + t * 4 + kcl) * 64 + l) * 8) = o;
    }
}

// ---------------------------------------------------------------------------
// Fusion, rank-split + LDS-staged A (R15-measured best ~90us).
// ---------------------------------------------------------------------------
template<int NKC>
__device__ __forceinline__ void fusion_pass_lds(
    const unsigned short* __restrict__ ldsA, int cbase,
    const unsigned short* __restrict__ wp,
    const float* __restrict__ W, int K, int w, int l, f32x4 (&acc)[4])
{
    const int c_lo = l & 15;
#pragma unroll
    for (int ct = 0; ct < 4; ++ct) {
        float wi = W[((size_t)w * K + (K - 1)) * 64 + ct * 16 + c_lo];
        acc[ct] = f32x4{wi, wi, wi, wi};
    }
#pragma unroll
    for (int kc = 0; kc < NKC; ++kc) {
        bf16x8 af = *(const bf16x8*)(ldsA + (cbase + kc) * 512 + l * 8);
        const unsigned short* wk = wp + (size_t)kc * 8192 + w * 512 + l * 8;
#pragma unroll
        for (int ct = 0; ct < 4; ++ct) {
            bf16x8 bf = *(const bf16x8*)(wk + ct * 2048);
            acc[ct] = __builtin_amdgcn_mfma_f32_16x16x32_bf16(af, bf, acc[ct], 0, 0, 0);
        }
    }
}

__global__ __launch_bounds__(256) void fusion_mfma(
    const unsigned short* __restrict__ apc, const unsigned short* __restrict__ apt,
    const unsigned short* __restrict__ apr,
    const unsigned short* __restrict__ wpc, const unsigned short* __restrict__ wpt,
    const unsigned short* __restrict__ wpr,
    const float* __restrict__ Wc, const float* __restrict__ Wt, const float* __restrict__ Wr,
    const float* __restrict__ fw, const float* __restrict__ fb,
    unsigned short* __restrict__ h0b)
{
    __shared__ __align__(16) char smem[36864];
    unsigned short* ldsA = (unsigned short*)smem;
    float* ldsx = (float*)smem;
    const int w = threadIdx.x >> 6, l = threadIdx.x & 63;
    const int G = blockIdx.x;

#pragma unroll
    for (int j = 0; j < 9; ++j) {
        int cid = w * 9 + j;
        const unsigned short* s;
        if (cid < 4)       s = apc + ((size_t)G * 4  + cid) * 512;
        else if (cid < 20) s = apt + ((size_t)G * 16 + (cid - 4)) * 512;
        else               s = apr + ((size_t)G * 16 + (cid - 20)) * 512;
        gld_lds16(s + l * 8, ldsA + cid * 512);
    }
    __syncthreads();

    f32x4 prod[4], acc[4];
    fusion_pass_lds<4>(ldsA, 0, wpc, Wc, 129, w, l, acc);
#pragma unroll
    for (int ct = 0; ct < 4; ++ct) prod[ct] = acc[ct];
    fusion_pass_lds<16>(ldsA, 4, wpt, Wt, 513, w, l, acc);
#pragma unroll
    for (int ct = 0; ct < 4; ++ct) prod[ct] *= acc[ct];
    fusion_pass_lds<16>(ldsA, 20, wpr, Wr, 513, w, l, acc);
    const float fww = fw[w];
#pragma unroll
    for (int ct = 0; ct < 4; ++ct) prod[ct] = prod[ct] * acc[ct] * fww;

    __syncthreads();
#pragma unroll
    for (int ct = 0; ct < 4; ++ct)
        *(f32x4*)&ldsx[((w * 4 + ct) * 64 + l) * 4] = prod[ct];
    __syncthreads();

    f32x4 s = *(const f32x4*)&ldsx[((0 * 4 + w) * 64 + l) * 4];
#pragma unroll
    for (int r = 1; r < 4; ++r)
        s += *(const f32x4*)&ldsx[((r * 4 + w) * 64 + l) * 4];

    const int c = w * 16 + (l & 15);
    const float fbc = fb[c];
#pragma unroll
    for (int q = 0; q < 4; ++q) {
        int n = G * 16 + (l >> 4) * 4 + q;
        float v = s[q] + fbc;
        v = v > 0.f ? v : expm1f(v);
        h0b[(size_t)n * 64 + c] = f2b(v);
    }
}

// ---------------------------------------------------------------------------
// feat GEMM with FUSED el/er epilogue. HEAD-MINOR output featb[n][d*4+h].
// ---------------------------------------------------------------------------
template<int K>
__global__ __launch_bounds__(256) void gemm_reg(
    const unsigned short* __restrict__ Ab, const unsigned short* __restrict__ wp,
    const float* __restrict__ al, const float* __restrict__ ar,
    unsigned short* __restrict__ featb,
    float* __restrict__ el, float* __restrict__ er)
{
    constexpr int NKC = K / 32;
    const int w = threadIdx.x >> 6, l = threadIdx.x & 63;
    const int nb = blockIdx.x * 16;

    f32x4 acc[4];
#pragma unroll
    for (int i = 0; i < 4; ++i) acc[i] = f32x4{0.f, 0.f, 0.f, 0.f};

    const unsigned short* abase = Ab + (size_t)(nb + (l & 15)) * K + (l >> 4) * 8;
    bf16x8 afs[NKC];
#pragma unroll
    for (int kc = 0; kc < NKC; ++kc)
        afs[kc] = *(const bf16x8*)(abase + kc * 32);

    bf16x8 bcur[4];
    {
        const unsigned short* wk = wp + (size_t)(0 * 16 + w * 4) * 512 + l * 8;
#pragma unroll
        for (int i = 0; i < 4; ++i) bcur[i] = *(const bf16x8*)(wk + i * 512);
    }
#pragma unroll
    for (int kc = 0; kc < NKC; ++kc) {
        bf16x8 bnxt[4];
        if (kc + 1 < NKC) {
            const unsigned short* wk = wp + ((size_t)(kc + 1) * 16 + w * 4) * 512 + l * 8;
#pragma unroll
            for (int i = 0; i < 4; ++i) bnxt[i] = *(const bf16x8*)(wk + i * 512);
        }
#pragma unroll
        for (int i = 0; i < 4; ++i)
            acc[i] = __builtin_amdgcn_mfma_f32_16x16x32_bf16(afs[kc], bcur[i], acc[i], 0, 0, 0);
        if (kc + 1 < NKC) {
#pragma unroll
            for (int i = 0; i < 4; ++i) bcur[i] = bnxt[i];
        }
    }

#pragma unroll
    for (int i = 0; i < 4; ++i) {
        int c = (w * 4 + i) * 16 + (l & 15);
        int dm = (c & 63) * 4 + (c >> 6);
#pragma unroll
        for (int q = 0; q < 4; ++q) {
            int n = nb + (l >> 4) * 4 + q;
            featb[(size_t)n * 256 + dm] = f2b(acc[i][q]);
        }
    }

    float pel[4] = {0.f, 0.f, 0.f, 0.f};
    float per_[4] = {0.f, 0.f, 0.f, 0.f};
#pragma unroll
    for (int i = 0; i < 4; ++i) {
        int d = i * 16 + (l & 15);
        float av = al[w * 64 + d];
        float rv = ar[w * 64 + d];
#pragma unroll
        for (int q = 0; q < 4; ++q) {
            pel[q] += acc[i][q] * av;
            per_[q] += acc[i][q] * rv;
        }
    }
#pragma unroll
    for (int off = 1; off <= 8; off <<= 1) {
#pragma unroll
        for (int q = 0; q < 4; ++q) {
            pel[q] += __shfl_xor(pel[q], off);
            per_[q] += __shfl_xor(per_[q], off);
        }
    }
    int qsel = l & 15;
    if (qsel < 4) {
        float ev = qsel == 0 ? pel[0] : qsel == 1 ? pel[1] : qsel == 2 ? pel[2] : pel[3];
        float rv = qsel == 0 ? per_[0] : qsel == 1 ? per_[1] : qsel == 2 ? per_[2] : per_[3];
        int n = nb + (l >> 4) * 4 + qsel;
        el[(size_t)n * 4 + w] = ev;
        er[(size_t)n * 4 + w] = rv;
    }
}

// ---------------------------------------------------------------------------
// CSR build
// ---------------------------------------------------------------------------
__global__ void hist_kernel(const int* __restrict__ dst, int* __restrict__ cnt)
{
    int e = blockIdx.x * blockDim.x + threadIdx.x;
    if (e < EE) atomicAdd(&cnt[dst[e]], 1);
}

__global__ __launch_bounds__(1024) void scan_kernel(const int* __restrict__ cnt, int* __restrict__ offs)
{
    __shared__ int tmp[1024];
    const int t = threadIdx.x;
    const int C = (NN + 1023) / 1024;
    int lo = t * C, hi = min(lo + C, NN);
    int s = 0;
    for (int i = lo; i < hi; ++i) s += cnt[i];
    tmp[t] = s;
    __syncthreads();
    for (int off = 1; off < 1024; off <<= 1) {
        int v = (t >= off) ? tmp[t - off] : 0;
        __syncthreads();
        tmp[t] += v;
        __syncthreads();
    }
    int run = (t == 0) ? 0 : tmp[t - 1];
    for (int i = lo; i < hi; ++i) { offs[i] = run; run += cnt[i]; }
    if (t == 1023) offs[NN] = tmp[1023];
}

__global__ void scatter_kernel(const int* __restrict__ dst, const int* __restrict__ offs,
                               int* __restrict__ cur, int* __restrict__ esort)
{
    int e = blockIdx.x * blockDim.x + threadIdx.x;
    if (e < EE) {
        int d = dst[e];
        int p = offs[d] + atomicAdd(&cur[d], 1);
        esort[p] = e;
    }
}

// ---------------------------------------------------------------------------
// gat_agg, register-cached softmax (deg<=64 fast path; lane p owns one edge).
// Computes logits in-kernel (el L2-resident) -> edge_prep / eesort / srcsort
// and att_final all deleted. Attention written per-lane into att[e].
// ---------------------------------------------------------------------------
template <int RESID, int WATT, int WB16, int WF32>
__global__ __launch_bounds__(256) void gat_agg(
    const int* __restrict__ esort, const int* __restrict__ src, const int* __restrict__ offs,
    const unsigned short* __restrict__ featb,
    const float* __restrict__ el, const float* __restrict__ er,
    const unsigned short* __restrict__ residb, const float* __restrict__ bias,
    float* __restrict__ out, unsigned short* __restrict__ outb,
    float4* __restrict__ att)
{
    int n = (int)((blockIdx.x * (size_t)blockDim.x + threadIdx.x) >> 6);
    int lane = threadIdx.x & 63;
    if (n >= NN) return;
    const int s0 = offs[n], s1 = offs[n + 1], deg = s1 - s0;
    const float4 r4 = *(const float4*)(er + (size_t)n * 4);

    float a0 = 0.f, a1 = 0.f, a2 = 0.f, a3 = 0.f;
    float i0, i1, i2, i3;

    if (deg <= 64) {
        // ---- fast path: lane owns edge p = s0+lane ----
        int p = s0 + lane;
        bool valid = p < s1;
        int e = valid ? esort[p] : 0;
        int sv = valid ? src[e] : 0;
        float v0 = -1e30f, v1 = -1e30f, v2 = -1e30f, v3 = -1e30f;
        if (valid) {
            float4 l4 = *(const float4*)(el + (size_t)sv * 4);
            v0 = lrelu(l4.x + r4.x); v1 = lrelu(l4.y + r4.y);
            v2 = lrelu(l4.z + r4.z); v3 = lrelu(l4.w + r4.w);
        }
        float m0 = v0, m1 = v1, m2 = v2, m3 = v3;
#pragma unroll
        for (int off = 32; off; off >>= 1) {
            m0 = fmaxf(m0, __shfl_xor(m0, off));
            m1 = fmaxf(m1, __shfl_xor(m1, off));
            m2 = fmaxf(m2, __shfl_xor(m2, off));
            m3 = fmaxf(m3, __shfl_xor(m3, off));
        }
        float e0 = valid ? expf(v0 - m0) : 0.f;
        float e1 = valid ? expf(v1 - m1) : 0.f;
        float e2 = valid ? expf(v2 - m2) : 0.f;
        float e3 = valid ? expf(v3 - m3) : 0.f;
        float z0 = e0, z1 = e1, z2 = e2, z3 = e3;
#pragma unroll
        for (int off = 32; off; off >>= 1) {
            z0 += __shfl_xor(z0, off);
            z1 += __shfl_xor(z1, off);
            z2 += __shfl_xor(z2, off);
            z3 += __shfl_xor(z3, off);
        }
        float j0 = z0 > 0.f ? 1.f / z0 : 0.f;
        float j1 = z1 > 0.f ? 1.f / z1 : 0.f;
        float j2 = z2 > 0.f ? 1.f / z2 : 0.f;
        float j3 = z3 > 0.f ? 1.f / z3 : 0.f;
        // pre-scale: per-lane attention for its own edge
        e0 *= j0; e1 *= j1; e2 *= j2; e3 *= j3;
        if (WATT && valid)
            att[e] = make_float4(e0, e1, e2, e3);
        for (int jj = 0; jj < deg; ++jj) {
            float w0 = __shfl(e0, jj), w1 = __shfl(e1, jj);
            float w2 = __shfl(e2, jj), w3 = __shfl(e3, jj);
            int s = __shfl(sv, jj);
            ushort4 f = *(const ushort4*)(featb + (size_t)s * 256 + lane * 4);
            a0 += w0 * b2f(f.x);
            a1 += w1 * b2f(f.y);
            a2 += w2 * b2f(f.z);
            a3 += w3 * b2f(f.w);
        }
        i0 = i1 = i2 = i3 = 1.f;   // already scaled
    } else {
        // ---- slow path (deg > 64, ~never): recompute logits per pass ----
        float m0 = -1e30f, m1 = -1e30f, m2 = -1e30f, m3 = -1e30f;
        for (int p = s0 + lane; p < s1; p += 64) {
            int s = src[esort[p]];
            float4 l4 = *(const float4*)(el + (size_t)s * 4);
            m0 = fmaxf(m0, lrelu(l4.x + r4.x));
            m1 = fmaxf(m1, lrelu(l4.y + r4.y));
            m2 = fmaxf(m2, lrelu(l4.z + r4.z));
            m3 = fmaxf(m3, lrelu(l4.w + r4.w));
        }
#pragma unroll
        for (int off = 32; off; off >>= 1) {
            m0 = fmaxf(m0, __shfl_xor(m0, off));
            m1 = fmaxf(m1, __shfl_xor(m1, off));
            m2 = fmaxf(m2, __shfl_xor(m2, off));
            m3 = fmaxf(m3, __shfl_xor(m3, off));
        }
        float z0 = 0.f, z1 = 0.f, z2 = 0.f, z3 = 0.f;
        for (int p = s0 + lane; p < s1; p += 64) {
            int s = src[esort[p]];
            float4 l4 = *(const float4*)(el + (size_t)s * 4);
            z0 += expf(lrelu(l4.x + r4.x) - m0);
            z1 += expf(lrelu(l4.y + r4.y) - m1);
            z2 += expf(lrelu(l4.z + r4.z) - m2);
            z3 += expf(lrelu(l4.w + r4.w) - m3);
        }
#pragma unroll
        for (int off = 32; off; off >>= 1) {
            z0 += __shfl_xor(z0, off);
            z1 += __shfl_xor(z1, off);
            z2 += __shfl_xor(z2, off);
            z3 += __shfl_xor(z3, off);
        }
        i0 = z0 > 0.f ? 1.f / z0 : 0.f;
        i1 = z1 > 0.f ? 1.f / z1 : 0.f;
        i2 = z2 > 0.f ? 1.f / z2 : 0.f;
        i3 = z3 > 0.f ? 1.f / z3 : 0.f;
        for (int p = s0; p < s1; ++p) {
            int e = esort[p];
            int s = src[e];
            float4 l4 = *(const float4*)(el + (size_t)s * 4);
            float w0 = expf(lrelu(l4.x + r4.x) - m0);
            float w1 = expf(lrelu(l4.y + r4.y) - m1);
            float w2 = expf(lrelu(l4.z + r4.z) - m2);
            float w3 = expf(lrelu(l4.w + r4.w) - m3);
            ushort4 f = *(const ushort4*)(featb + (size_t)s * 256 + lane * 4);
            a0 += w0 * b2f(f.x);
            a1 += w1 * b2f(f.y);
            a2 += w2 * b2f(f.z);
            a3 += w3 * b2f(f.w);
            if (WATT && lane == 0)
                att[e] = make_float4(w0 * i0, w1 * i1, w2 * i2, w3 * i3);
        }
    }

    float o0 = a0 * i0 + bias[lane];
    float o1 = a1 * i1 + bias[64 + lane];
    float o2 = a2 * i2 + bias[128 + lane];
    float o3 = a3 * i3 + bias[192 + lane];
    if (RESID) {
        ushort4 rp = *(const ushort4*)(residb + (size_t)n * 256 + lane * 4);
        o0 += b2f(rp.x); o1 += b2f(rp.y); o2 += b2f(rp.z); o3 += b2f(rp.w);
    }
    if (WF32) {
        float* op = out + (size_t)n * 256;
        op[lane] = o0;
        op[64 + lane] = o1;
        op[128 + lane] = o2;
        op[192 + lane] = o3;
    }
    if (WB16) {
        ushort4 ob;
        ob.x = f2b(o0); ob.y = f2b(o1); ob.z = f2b(o2); ob.w = f2b(o3);
        *(ushort4*)(outb + (size_t)n * 256 + lane * 4) = ob;
    }
}

// ---------------------------------------------------------------------------
extern "C" void kernel_launch(void* const* d_in, const int* in_sizes, int n_in,
                              void* d_out, int out_size, void* d_ws, size_t ws_size,
                              hipStream_t stream)
{
    const int*   src = (const int*)d_in[0];
    const int*   dst = (const int*)d_in[1];
    const float* hc  = (const float*)d_in[2];
    const float* ht  = (const float*)d_in[3];
    const float* hr  = (const float*)d_in[4];
    const float* Wc  = (const float*)d_in[5];
    const float* Wt  = (const float*)d_in[6];
    const float* Wr  = (const float*)d_in[7];
    const float* fw  = (const float*)d_in[8];
    const float* fb  = (const float*)d_in[9];
    const float* W0  = (const float*)d_in[10];
    const float* al0 = (const float*)d_in[11];
    const float* ar0 = (const float*)d_in[12];
    const float* b0  = (const float*)d_in[13];
    const float* W1  = (const float*)d_in[14];
    const float* al1 = (const float*)d_in[15];
    const float* ar1 = (const float*)d_in[16];
    const float* b1  = (const float*)d_in[17];

    // workspace layout (bytes); rounds 8-15 proved ws_size >= 68,353,792
    char* ws = (char*)d_ws;
    unsigned short* h0b   = (unsigned short*)(ws);               // N*64  bf16 :  6,400,000
    unsigned short* h1b   = (unsigned short*)(ws + 6400000);     // N*256 bf16 : 25,600,000 (head-minor)
    unsigned short* featb = (unsigned short*)(ws + 32000000);    // N*256 bf16 : 25,600,000 (head-minor)
    float* el    = (float*)(ws + 57600000);                      //    800,000
    float* er    = (float*)(ws + 58400000);                      //    800,000
    int*   cnt   = (int*)  (ws + 59200000);                      //    200,000
    int*   offs  = (int*)  (ws + 59400000);                      //    200,064 (padded)
    int*   esort = (int*)  (ws + 59600128);                      //  3,200,000
    unsigned short* wpc = (unsigned short*)(ws + 62800128);      //  4*16KB =  65,536
    unsigned short* wpt = (unsigned short*)(ws + 62865664);      // 16*16KB = 262,144
    unsigned short* wpr = (unsigned short*)(ws + 63127808);      // 16*16KB = 262,144
    unsigned short* wp0 = (unsigned short*)(ws + 63389952);      //  2*16KB =  32,768
    unsigned short* wp1 = (unsigned short*)(ws + 63422720);      //  8*16KB = 131,072
    if (ws_size < 63553792ull) return;                           // end of layout

    float* outh = (float*)d_out;                       // N*256 final h
    float4* atto = (float4*)(outh + (size_t)NN * 256); // E*4 att region

    // A-pack overlays (live only during fusion)
    unsigned short* apt = (unsigned short*)d_out;                     // 51,200,000
    unsigned short* apc = (unsigned short*)((char*)d_out + 51200000); // 12,800,000
    unsigned short* apr = (unsigned short*)(ws + 6400000);            // 51,200,000

    // weight packing
    pack_w_fusion<<<(4 * 16 * 64 + 255) / 256, 256, 0, stream>>>(Wc, wpc, 129, 4);
    pack_w_fusion<<<(16 * 16 * 64 + 255) / 256, 256, 0, stream>>>(Wt, wpt, 513, 16);
    pack_w_fusion<<<(16 * 16 * 64 + 255) / 256, 256, 0, stream>>>(Wr, wpr, 513, 16);
    pack_w_gemm<0><<<(2 * 16 * 64 + 255) / 256, 256, 0, stream>>>(W0, wp0, 64, 256);
    pack_w_gemm<1><<<(8 * 16 * 64 + 255) / 256, 256, 0, stream>>>(W1, wp1, 256, 256);

    // F1: feature packs (f32 -> bf16 A-fragment order), 128-k tiles
    pack_a_tile<129, 4><<<NG * 1, 256, 0, stream>>>(hc, apc);
    pack_a_tile<513, 16><<<NG * 4, 256, 0, stream>>>(ht, apt);
    pack_a_tile<513, 16><<<NG * 4, 256, 0, stream>>>(hr, apr);

    // F2: trilinear fusion (rank-split, LDS-staged A)
    fusion_mfma<<<NG, 256, 0, stream>>>(apc, apt, apr, wpc, wpt, wpr,
                                        Wc, Wt, Wr, fw, fb, h0b);

    // CSR by dst
    hipMemsetAsync(cnt, 0, NN * sizeof(int), stream);
    hist_kernel<<<(EE + 255) / 256, 256, 0, stream>>>(dst, cnt);
    scan_kernel<<<1, 1024, 0, stream>>>(cnt, offs);
    hipMemsetAsync(cnt, 0, NN * sizeof(int), stream);
    scatter_kernel<<<(EE + 255) / 256, 256, 0, stream>>>(dst, offs, cnt, esort);

    // GAT layer 0: feat + el/er fused; softmax+agg in-register; bf16 h1b out
    gemm_reg<64><<<NG, 256, 0, stream>>>(h0b, wp0, al0, ar0, featb, el, er);
    gat_agg<0, 0, 1, 0><<<(NN * 64 + 255) / 256, 256, 0, stream>>>(
        esort, src, offs, featb, el, er, nullptr, b0, nullptr, h1b, nullptr);

    // GAT layer 1: residual from bf16 h1b; f32 out + attention (per-lane)
    gemm_reg<256><<<NG, 256, 0, stream>>>(h1b, wp1, al1, ar1, featb, el, er);
    gat_agg<1, 1, 0, 1><<<(NN * 64 + 255) / 256, 256, 0, stream>>>(
        esort, src, offs, featb, el, er, h1b, b1, outh, nullptr, atto);
}

// Round 17
// 531.529 us; speedup vs baseline: 1.1992x; 1.0327x over previous
//
#include <hip/hip_runtime.h>
#include <math.h>

#define NN 50000
#define EE 800000
#define NEG 0.2f
#define NG (NN / 16)   // 3125 node groups
#define CHDW 576       // dwords per staged chunk (16 rows x 36, pad 32->36)

using f32x4  = __attribute__((ext_vector_type(4))) float;
using bf16x8 = __attribute__((ext_vector_type(8))) short;

__device__ __forceinline__ float lrelu(float x){ return x > 0.f ? x : NEG*x; }

__device__ __forceinline__ unsigned short f2b(float f){
    unsigned int u = __float_as_uint(f);
    return (unsigned short)((u + 0x7FFFu + ((u >> 16) & 1u)) >> 16);  // RNE
}
__device__ __forceinline__ float b2f(unsigned short h){
    return __uint_as_float(((unsigned int)h) << 16);
}
__device__ __forceinline__ void gld_lds4(const void* g, void* l){
    __builtin_amdgcn_global_load_lds(
        (const __attribute__((address_space(1))) unsigned int*)g,
        (__attribute__((address_space(3))) unsigned int*)l, 4, 0, 0);
}
__device__ __forceinline__ unsigned int cvtpk(float lo, float hi){
    unsigned int r;
    asm volatile("v_cvt_pk_bf16_f32 %0, %1, %2" : "=v"(r) : "v"(lo), "v"(hi));
    return r;
}

// ---------------------------------------------------------------------------
// Combined weight packer (1 dispatch). Fragment-order bf16.
// Fusion layout: [kc][chunk=ct*4+r][lane][8], k < K-1 only (ones-row via init).
// GEMM layout:   [kc][ct][lane][8]; PERM=1 permutes k to head-minor A rows.
// ---------------------------------------------------------------------------
__device__ __forceinline__ void pw_fusion_body(
    const float* __restrict__ W, unsigned short* __restrict__ out, int K, int u)
{
    int l = u & 63, chunk = (u >> 6) & 15, kc = u >> 10;
    int ct = chunk >> 2, r = chunk & 3;
    int c = ct * 16 + (l & 15);
    int kb = kc * 32 + (l >> 4) * 8;
    bf16x8 v;
#pragma unroll
    for (int j = 0; j < 8; ++j)
        v[j] = (short)f2b(W[((size_t)r * K + kb + j) * 64 + c]);
    *(bf16x8*)(out + (size_t)u * 8) = v;
}

__device__ __forceinline__ void pw_gemm_body(
    const float* __restrict__ W, unsigned short* __restrict__ out,
    int C, int PERM, int u)
{
    int NCH = C / 16;
    int l = u & 63, ch = (u >> 6) % NCH, kc = u / (64 * NCH);
    int c = ch * 16 + (l & 15);
    int kb = kc * 32 + (l >> 4) * 8;
    bf16x8 v;
#pragma unroll
    for (int j = 0; j < 8; ++j) {
        int k = kb + j;
        int ko = PERM ? ((k & 3) * 64 + (k >> 2)) : k;
        v[j] = (short)f2b(W[(size_t)ko * C + c]);
    }
    *(bf16x8*)(out + (size_t)u * 8) = v;
}

__global__ __launch_bounds__(256) void pack_all_w(
    const float* __restrict__ Wc, const float* __restrict__ Wt, const float* __restrict__ Wr,
    const float* __restrict__ W0, const float* __restrict__ W1,
    unsigned short* __restrict__ wpc, unsigned short* __restrict__ wpt,
    unsigned short* __restrict__ wpr, unsigned short* __restrict__ wp0,
    unsigned short* __restrict__ wp1)
{
    int b = blockIdx.x, t = threadIdx.x;
    if (b < 16)        pw_fusion_body(Wc, wpc, 129, b * 256 + t);            // 4096
    else if (b < 80)   pw_fusion_body(Wt, wpt, 513, (b - 16) * 256 + t);     // 16384
    else if (b < 144)  pw_fusion_body(Wr, wpr, 513, (b - 80) * 256 + t);     // 16384
    else if (b < 152)  pw_gemm_body(W0, wp0, 256, 0, (b - 144) * 256 + t);   // 2048
    else               pw_gemm_body(W1, wp1, 256, 1, (b - 152) * 256 + t);   // 8192
}

// ---------------------------------------------------------------------------
// Fusion, rank-split + direct f32 LDS staging (pack_a folded in).
// Block = 4 waves on ONE 16-node group; wave w = rank w.
// Raw f32 features staged in two 18-chunk halves via gld_lds4 (row stride
// padded 32->36 dwords; pad slots clamp to k-offset 31, never read).
// A-frag: 2x f32x4 LDS read + v_cvt_pk_bf16_f32 x4. B-frags global (L2-hot).
// ---------------------------------------------------------------------------
__global__ __launch_bounds__(256) void fusion_mfma(
    const float* __restrict__ hc, const float* __restrict__ ht, const float* __restrict__ hr,
    const unsigned short* __restrict__ wpc, const unsigned short* __restrict__ wpt,
    const unsigned short* __restrict__ wpr,
    const float* __restrict__ Wc, const float* __restrict__ Wt, const float* __restrict__ Wr,
    const float* __restrict__ fw, const float* __restrict__ fb,
    unsigned short* __restrict__ h0b)
{
    __shared__ __align__(16) float lds[18 * CHDW];   // 41,472 B
    float* ldsx = lds;                               // aliased exchange (16KB)
    const int w = threadIdx.x >> 6, l = threadIdx.x & 63;
    const int G = blockIdx.x, nb = G * 16;
    const int c_lo = l & 15;

    // per-instruction row/koff (same for every chunk)
    int rowi[9], koffi[9];
#pragma unroll
    for (int i = 0; i < 9; ++i) {
        int u = i * 64 + l;
        rowi[i] = u / 36;
        int off = u - rowi[i] * 36;
        koffi[i] = off > 31 ? 31 : off;
    }

    // A-frag reader from staged f32 chunk slot
    const int abase_l = (l & 15) * 36 + (l >> 4) * 8;
    auto aread = [&](int slot) -> bf16x8 {
        const float* p = lds + slot * CHDW + abase_l;
        f32x4 a = *(const f32x4*)p;
        f32x4 b = *(const f32x4*)(p + 4);
        union { unsigned int wd[4]; bf16x8 v; } u;
        u.wd[0] = cvtpk(a[0], a[1]);
        u.wd[1] = cvtpk(a[2], a[3]);
        u.wd[2] = cvtpk(b[0], b[1]);
        u.wd[3] = cvtpk(b[2], b[3]);
        return u.v;
    };

    auto stage_half = [&](int half) {
        for (int cid = w; cid < 18; cid += 4) {
            int gcid = half * 18 + cid;
            const float* F; int K, kc;
            if (gcid < 4)       { F = hc; K = 129; kc = gcid; }
            else if (gcid < 20) { F = ht; K = 513; kc = gcid - 4; }
            else                { F = hr; K = 513; kc = gcid - 20; }
#pragma unroll
            for (int i = 0; i < 9; ++i) {
                const float* g = F + (size_t)(nb + rowi[i]) * K + kc * 32 + koffi[i];
                gld_lds4(g, (char*)(lds + cid * CHDW + i * 64));
            }
        }
    };

    f32x4 prod[4], accT[4], acc[4];

    // ---- half 0: hc chunks g0-3, ht kc0-13 (g4-17) ----
    stage_half(0);
    __syncthreads();

#pragma unroll
    for (int ct = 0; ct < 4; ++ct) {
        float wi = Wc[((size_t)w * 129 + 128) * 64 + ct * 16 + c_lo];
        prod[ct] = f32x4{wi, wi, wi, wi};
    }
#pragma unroll
    for (int kc = 0; kc < 4; ++kc) {
        bf16x8 af = aread(kc);
        const unsigned short* wk = wpc + (size_t)kc * 8192 + w * 512 + l * 8;
#pragma unroll
        for (int ct = 0; ct < 4; ++ct) {
            bf16x8 bf = *(const bf16x8*)(wk + ct * 2048);
            prod[ct] = __builtin_amdgcn_mfma_f32_16x16x32_bf16(af, bf, prod[ct], 0, 0, 0);
        }
    }
#pragma unroll
    for (int ct = 0; ct < 4; ++ct) {
        float wi = Wt[((size_t)w * 513 + 512) * 64 + ct * 16 + c_lo];
        accT[ct] = f32x4{wi, wi, wi, wi};
    }
#pragma unroll
    for (int kc = 0; kc < 14; ++kc) {
        bf16x8 af = aread(4 + kc);
        const unsigned short* wk = wpt + (size_t)kc * 8192 + w * 512 + l * 8;
#pragma unroll
        for (int ct = 0; ct < 4; ++ct) {
            bf16x8 bf = *(const bf16x8*)(wk + ct * 2048);
            accT[ct] = __builtin_amdgcn_mfma_f32_16x16x32_bf16(af, bf, accT[ct], 0, 0, 0);
        }
    }

    // ---- half 1: ht kc14-15 (g18-19 -> slots 0-1), hr kc0-15 (slots 2-17) ----
    __syncthreads();          // everyone done reading half 0
    stage_half(1);
    __syncthreads();          // half 1 staged (vmcnt drained)

#pragma unroll
    for (int kc = 14; kc < 16; ++kc) {
        bf16x8 af = aread(kc - 14);
        const unsigned short* wk = wpt + (size_t)kc * 8192 + w * 512 + l * 8;
#pragma unroll
        for (int ct = 0; ct < 4; ++ct) {
            bf16x8 bf = *(const bf16x8*)(wk + ct * 2048);
            accT[ct] = __builtin_amdgcn_mfma_f32_16x16x32_bf16(af, bf, accT[ct], 0, 0, 0);
        }
    }
#pragma unroll
    for (int ct = 0; ct < 4; ++ct) {
        prod[ct] *= accT[ct];
        float wi = Wr[((size_t)w * 513 + 512) * 64 + ct * 16 + c_lo];
        acc[ct] = f32x4{wi, wi, wi, wi};
    }
#pragma unroll
    for (int kc = 0; kc < 16; ++kc) {
        bf16x8 af = aread(2 + kc);
        const unsigned short* wk = wpr + (size_t)kc * 8192 + w * 512 + l * 8;
#pragma unroll
        for (int ct = 0; ct < 4; ++ct) {
            bf16x8 bf = *(const bf16x8*)(wk + ct * 2048);
            acc[ct] = __builtin_amdgcn_mfma_f32_16x16x32_bf16(af, bf, acc[ct], 0, 0, 0);
        }
    }
    const float fww = fw[w];
#pragma unroll
    for (int ct = 0; ct < 4; ++ct) prod[ct] = prod[ct] * acc[ct] * fww;

    // ---- rank exchange (aliased LDS) + epilogue ----
    __syncthreads();          // all A reads done before overwrite
#pragma unroll
    for (int ct = 0; ct < 4; ++ct)
        *(f32x4*)&ldsx[((w * 4 + ct) * 64 + l) * 4] = prod[ct];
    __syncthreads();

    f32x4 s = *(const f32x4*)&ldsx[((0 * 4 + w) * 64 + l) * 4];
#pragma unroll
    for (int r = 1; r < 4; ++r)
        s += *(const f32x4*)&ldsx[((r * 4 + w) * 64 + l) * 4];

    const int c = w * 16 + c_lo;
    const float fbc = fb[c];
#pragma unroll
    for (int q = 0; q < 4; ++q) {
        int n = nb + (l >> 4) * 4 + q;
        float v = s[q] + fbc;
        v = v > 0.f ? v : expm1f(v);
        h0b[(size_t)n * 64 + c] = f2b(v);
    }
}

// ---------------------------------------------------------------------------
// feat GEMM with FUSED el/er epilogue. HEAD-MINOR output featb[n][d*4+h].
// ---------------------------------------------------------------------------
template<int K>
__global__ __launch_bounds__(256) void gemm_reg(
    const unsigned short* __restrict__ Ab, const unsigned short* __restrict__ wp,
    const float* __restrict__ al, const float* __restrict__ ar,
    unsigned short* __restrict__ featb,
    float* __restrict__ el, float* __restrict__ er)
{
    constexpr int NKC = K / 32;
    const int w = threadIdx.x >> 6, l = threadIdx.x & 63;
    const int nb = blockIdx.x * 16;

    f32x4 acc[4];
#pragma unroll
    for (int i = 0; i < 4; ++i) acc[i] = f32x4{0.f, 0.f, 0.f, 0.f};

    const unsigned short* abase = Ab + (size_t)(nb + (l & 15)) * K + (l >> 4) * 8;
    bf16x8 afs[NKC];
#pragma unroll
    for (int kc = 0; kc < NKC; ++kc)
        afs[kc] = *(const bf16x8*)(abase + kc * 32);

    bf16x8 bcur[4];
    {
        const unsigned short* wk = wp + (size_t)(0 * 16 + w * 4) * 512 + l * 8;
#pragma unroll
        for (int i = 0; i < 4; ++i) bcur[i] = *(const bf16x8*)(wk + i * 512);
    }
#pragma unroll
    for (int kc = 0; kc < NKC; ++kc) {
        bf16x8 bnxt[4];
        if (kc + 1 < NKC) {
            const unsigned short* wk = wp + ((size_t)(kc + 1) * 16 + w * 4) * 512 + l * 8;
#pragma unroll
            for (int i = 0; i < 4; ++i) bnxt[i] = *(const bf16x8*)(wk + i * 512);
        }
#pragma unroll
        for (int i = 0; i < 4; ++i)
            acc[i] = __builtin_amdgcn_mfma_f32_16x16x32_bf16(afs[kc], bcur[i], acc[i], 0, 0, 0);
        if (kc + 1 < NKC) {
#pragma unroll
            for (int i = 0; i < 4; ++i) bcur[i] = bnxt[i];
        }
    }

#pragma unroll
    for (int i = 0; i < 4; ++i) {
        int c = (w * 4 + i) * 16 + (l & 15);
        int dm = (c & 63) * 4 + (c >> 6);
#pragma unroll
        for (int q = 0; q < 4; ++q) {
            int n = nb + (l >> 4) * 4 + q;
            featb[(size_t)n * 256 + dm] = f2b(acc[i][q]);
        }
    }

    float pel[4] = {0.f, 0.f, 0.f, 0.f};
    float per_[4] = {0.f, 0.f, 0.f, 0.f};
#pragma unroll
    for (int i = 0; i < 4; ++i) {
        int d = i * 16 + (l & 15);
        float av = al[w * 64 + d];
        float rv = ar[w * 64 + d];
#pragma unroll
        for (int q = 0; q < 4; ++q) {
            pel[q] += acc[i][q] * av;
            per_[q] += acc[i][q] * rv;
        }
    }
#pragma unroll
    for (int off = 1; off <= 8; off <<= 1) {
#pragma unroll
        for (int q = 0; q < 4; ++q) {
            pel[q] += __shfl_xor(pel[q], off);
            per_[q] += __shfl_xor(per_[q], off);
        }
    }
    int qsel = l & 15;
    if (qsel < 4) {
        float ev = qsel == 0 ? pel[0] : qsel == 1 ? pel[1] : qsel == 2 ? pel[2] : pel[3];
        float rv = qsel == 0 ? per_[0] : qsel == 1 ? per_[1] : qsel == 2 ? per_[2] : per_[3];
        int n = nb + (l >> 4) * 4 + qsel;
        el[(size_t)n * 4 + w] = ev;
        er[(size_t)n * 4 + w] = rv;
    }
}

// ---------------------------------------------------------------------------
// CSR build (scan re-zeroes cnt for scatter -> second memset deleted)
// ---------------------------------------------------------------------------
__global__ void hist_kernel(const int* __restrict__ dst, int* __restrict__ cnt)
{
    int e = blockIdx.x * blockDim.x + threadIdx.x;
    if (e < EE) atomicAdd(&cnt[dst[e]], 1);
}

__global__ __launch_bounds__(1024) void scan_kernel(int* __restrict__ cnt, int* __restrict__ offs)
{
    __shared__ int tmp[1024];
    const int t = threadIdx.x;
    const int C = (NN + 1023) / 1024;
    int lo = t * C, hi = min(lo + C, NN);
    int s = 0;
    for (int i = lo; i < hi; ++i) s += cnt[i];
    tmp[t] = s;
    __syncthreads();
    for (int off = 1; off < 1024; off <<= 1) {
        int v = (t >= off) ? tmp[t - off] : 0;
        __syncthreads();
        tmp[t] += v;
        __syncthreads();
    }
    int run = (t == 0) ? 0 : tmp[t - 1];
    for (int i = lo; i < hi; ++i) { offs[i] = run; run += cnt[i]; cnt[i] = 0; }
    if (t == 1023) offs[NN] = tmp[1023];
}

__global__ void scatter_kernel(const int* __restrict__ dst, const int* __restrict__ offs,
                               int* __restrict__ cur, int* __restrict__ esort)
{
    int e = blockIdx.x * blockDim.x + threadIdx.x;
    if (e < EE) {
        int d = dst[e];
        int p = offs[d] + atomicAdd(&cur[d], 1);
        esort[p] = e;
    }
}

// ---------------------------------------------------------------------------
// gat_agg, register-cached softmax (deg<=64 fast path; lane owns one edge).
// ---------------------------------------------------------------------------
template <int RESID, int WATT, int WB16, int WF32>
__global__ __launch_bounds__(256) void gat_agg(
    const int* __restrict__ esort, const int* __restrict__ src, const int* __restrict__ offs,
    const unsigned short* __restrict__ featb,
    const float* __restrict__ el, const float* __restrict__ er,
    const unsigned short* __restrict__ residb, const float* __restrict__ bias,
    float* __restrict__ out, unsigned short* __restrict__ outb,
    float4* __restrict__ att)
{
    int n = (int)((blockIdx.x * (size_t)blockDim.x + threadIdx.x) >> 6);
    int lane = threadIdx.x & 63;
    if (n >= NN) return;
    const int s0 = offs[n], s1 = offs[n + 1], deg = s1 - s0;
    const float4 r4 = *(const float4*)(er + (size_t)n * 4);

    float a0 = 0.f, a1 = 0.f, a2 = 0.f, a3 = 0.f;
    float i0, i1, i2, i3;

    if (deg <= 64) {
        int p = s0 + lane;
        bool valid = p < s1;
        int e = valid ? esort[p] : 0;
        int sv = valid ? src[e] : 0;
        float v0 = -1e30f, v1 = -1e30f, v2 = -1e30f, v3 = -1e30f;
        if (valid) {
            float4 l4 = *(const float4*)(el + (size_t)sv * 4);
            v0 = lrelu(l4.x + r4.x); v1 = lrelu(l4.y + r4.y);
            v2 = lrelu(l4.z + r4.z); v3 = lrelu(l4.w + r4.w);
        }
        float m0 = v0, m1 = v1, m2 = v2, m3 = v3;
#pragma unroll
        for (int off = 32; off; off >>= 1) {
            m0 = fmaxf(m0, __shfl_xor(m0, off));
            m1 = fmaxf(m1, __shfl_xor(m1, off));
            m2 = fmaxf(m2, __shfl_xor(m2, off));
            m3 = fmaxf(m3, __shfl_xor(m3, off));
        }
        float e0 = valid ? expf(v0 - m0) : 0.f;
        float e1 = valid ? expf(v1 - m1) : 0.f;
        float e2 = valid ? expf(v2 - m2) : 0.f;
        float e3 = valid ? expf(v3 - m3) : 0.f;
        float z0 = e0, z1 = e1, z2 = e2, z3 = e3;
#pragma unroll
        for (int off = 32; off; off >>= 1) {
            z0 += __shfl_xor(z0, off);
            z1 += __shfl_xor(z1, off);
            z2 += __shfl_xor(z2, off);
            z3 += __shfl_xor(z3, off);
        }
        float j0 = z0 > 0.f ? 1.f / z0 : 0.f;
        float j1 = z1 > 0.f ? 1.f / z1 : 0.f;
        float j2 = z2 > 0.f ? 1.f / z2 : 0.f;
        float j3 = z3 > 0.f ? 1.f / z3 : 0.f;
        e0 *= j0; e1 *= j1; e2 *= j2; e3 *= j3;
        if (WATT && valid)
            att[e] = make_float4(e0, e1, e2, e3);
        for (int jj = 0; jj < deg; ++jj) {
            float w0 = __shfl(e0, jj), w1 = __shfl(e1, jj);
            float w2 = __shfl(e2, jj), w3 = __shfl(e3, jj);
            int s = __shfl(sv, jj);
            ushort4 f = *(const ushort4*)(featb + (size_t)s * 256 + lane * 4);
            a0 += w0 * b2f(f.x);
            a1 += w1 * b2f(f.y);
            a2 += w2 * b2f(f.z);
            a3 += w3 * b2f(f.w);
        }
        i0 = i1 = i2 = i3 = 1.f;
    } else {
        float m0 = -1e30f, m1 = -1e30f, m2 = -1e30f, m3 = -1e30f;
        for (int p = s0 + lane; p < s1; p += 64) {
            int s = src[esort[p]];
            float4 l4 = *(const float4*)(el + (size_t)s * 4);
            m0 = fmaxf(m0, lrelu(l4.x + r4.x));
            m1 = fmaxf(m1, lrelu(l4.y + r4.y));
            m2 = fmaxf(m2, lrelu(l4.z + r4.z));
            m3 = fmaxf(m3, lrelu(l4.w + r4.w));
        }
#pragma unroll
        for (int off = 32; off; off >>= 1) {
            m0 = fmaxf(m0, __shfl_xor(m0, off));
            m1 = fmaxf(m1, __shfl_xor(m1, off));
            m2 = fmaxf(m2, __shfl_xor(m2, off));
            m3 = fmaxf(m3, __shfl_xor(m3, off));
        }
        float z0 = 0.f, z1 = 0.f, z2 = 0.f, z3 = 0.f;
        for (int p = s0 + lane; p < s1; p += 64) {
            int s = src[esort[p]];
            float4 l4 = *(const float4*)(el + (size_t)s * 4);
            z0 += expf(lrelu(l4.x + r4.x) - m0);
            z1 += expf(lrelu(l4.y + r4.y) - m1);
            z2 += expf(lrelu(l4.z + r4.z) - m2);
            z3 += expf(lrelu(l4.w + r4.w) - m3);
        }
#pragma unroll
        for (int off = 32; off; off >>= 1) {
            z0 += __shfl_xor(z0, off);
            z1 += __shfl_xor(z1, off);
            z2 += __shfl_xor(z2, off);
            z3 += __shfl_xor(z3, off);
        }
        i0 = z0 > 0.f ? 1.f / z0 : 0.f;
        i1 = z1 > 0.f ? 1.f / z1 : 0.f;
        i2 = z2 > 0.f ? 1.f / z2 : 0.f;
        i3 = z3 > 0.f ? 1.f / z3 : 0.f;
        for (int p = s0; p < s1; ++p) {
            int e = esort[p];
            int s = src[e];
            float4 l4 = *(const float4*)(el + (size_t)s * 4);
            float w0 = expf(lrelu(l4.x + r4.x) - m0);
            float w1 = expf(lrelu(l4.y + r4.y) - m1);
            float w2 = expf(lrelu(l4.z + r4.z) - m2);
            float w3 = expf(lrelu(l4.w + r4.w) - m3);
            ushort4 f = *(const ushort4*)(featb + (size_t)s * 256 + lane * 4);
            a0 += w0 * b2f(f.x);
            a1 += w1 * b2f(f.y);
            a2 += w2 * b2f(f.z);
            a3 += w3 * b2f(f.w);
            if (WATT && lane == 0)
                att[e] = make_float4(w0 * i0, w1 * i1, w2 * i2, w3 * i3);
        }
    }

    float o0 = a0 * i0 + bias[lane];
    float o1 = a1 * i1 + bias[64 + lane];
    float o2 = a2 * i2 + bias[128 + lane];
    float o3 = a3 * i3 + bias[192 + lane];
    if (RESID) {
        ushort4 rp = *(const ushort4*)(residb + (size_t)n * 256 + lane * 4);
        o0 += b2f(rp.x); o1 += b2f(rp.y); o2 += b2f(rp.z); o3 += b2f(rp.w);
    }
    if (WF32) {
        float* op = out + (size_t)n * 256;
        op[lane] = o0;
        op[64 + lane] = o1;
        op[128 + lane] = o2;
        op[192 + lane] = o3;
    }
    if (WB16) {
        ushort4 ob;
        ob.x = f2b(o0); ob.y = f2b(o1); ob.z = f2b(o2); ob.w = f2b(o3);
        *(ushort4*)(outb + (size_t)n * 256 + lane * 4) = ob;
    }
}

// ---------------------------------------------------------------------------
extern "C" void kernel_launch(void* const* d_in, const int* in_sizes, int n_in,
                              void* d_out, int out_size, void* d_ws, size_t ws_size,
                              hipStream_t stream)
{
    const int*   src = (const int*)d_in[0];
    const int*   dst = (const int*)d_in[1];
    const float* hc  = (const float*)d_in[2];
    const float* ht  = (const float*)d_in[3];
    const float* hr  = (const float*)d_in[4];
    const float* Wc  = (const float*)d_in[5];
    const float* Wt  = (const float*)d_in[6];
    const float* Wr  = (const float*)d_in[7];
    const float* fw  = (const float*)d_in[8];
    const float* fb  = (const float*)d_in[9];
    const float* W0  = (const float*)d_in[10];
    const float* al0 = (const float*)d_in[11];
    const float* ar0 = (const float*)d_in[12];
    const float* b0  = (const float*)d_in[13];
    const float* W1  = (const float*)d_in[14];
    const float* al1 = (const float*)d_in[15];
    const float* ar1 = (const float*)d_in[16];
    const float* b1  = (const float*)d_in[17];

    // workspace layout (bytes); rounds 8-16 proved ws_size >= 63,553,792
    char* ws = (char*)d_ws;
    unsigned short* h0b   = (unsigned short*)(ws);               // N*64  bf16 :  6,400,000
    unsigned short* h1b   = (unsigned short*)(ws + 6400000);     // N*256 bf16 : 25,600,000 (head-minor)
    unsigned short* featb = (unsigned short*)(ws + 32000000);    // N*256 bf16 : 25,600,000 (head-minor)
    float* el    = (float*)(ws + 57600000);                      //    800,000
    float* er    = (float*)(ws + 58400000);                      //    800,000
    int*   cnt   = (int*)  (ws + 59200000);                      //    200,000
    int*   offs  = (int*)  (ws + 59400000);                      //    200,064 (padded)
    int*   esort = (int*)  (ws + 59600128);                      //  3,200,000
    unsigned short* wpc = (unsigned short*)(ws + 62800128);      //  4*16KB =  65,536
    unsigned short* wpt = (unsigned short*)(ws + 62865664);      // 16*16KB = 262,144
    unsigned short* wpr = (unsigned short*)(ws + 63127808);      // 16*16KB = 262,144
    unsigned short* wp0 = (unsigned short*)(ws + 63389952);      //  2*16KB =  32,768
    unsigned short* wp1 = (unsigned short*)(ws + 63422720);      //  8*16KB = 131,072
    if (ws_size < 63553792ull) return;                           // end of layout

    float* outh = (float*)d_out;                       // N*256 final h
    float4* atto = (float4*)(outh + (size_t)NN * 256); // E*4 att region

    // weight packing (single dispatch)
    pack_all_w<<<184, 256, 0, stream>>>(Wc, Wt, Wr, W0, W1, wpc, wpt, wpr, wp0, wp1);

    // trilinear fusion (rank-split, direct f32 LDS staging — pack_a folded in)
    fusion_mfma<<<NG, 256, 0, stream>>>(hc, ht, hr, wpc, wpt, wpr,
                                        Wc, Wt, Wr, fw, fb, h0b);

    // CSR by dst (scan re-zeroes cnt for scatter)
    hipMemsetAsync(cnt, 0, NN * sizeof(int), stream);
    hist_kernel<<<(EE + 255) / 256, 256, 0, stream>>>(dst, cnt);
    scan_kernel<<<1, 1024, 0, stream>>>(cnt, offs);
    scatter_kernel<<<(EE + 255) / 256, 256, 0, stream>>>(dst, offs, cnt, esort);

    // GAT layer 0: feat + el/er fused; softmax+agg in-register; bf16 h1b out
    gemm_reg<64><<<NG, 256, 0, stream>>>(h0b, wp0, al0, ar0, featb, el, er);
    gat_agg<0, 0, 1, 0><<<(NN * 64 + 255) / 256, 256, 0, stream>>>(
        esort, src, offs, featb, el, er, nullptr, b0, nullptr, h1b, nullptr);

    // GAT layer 1: residual from bf16 h1b; f32 out + attention (per-lane)
    gemm_reg<256><<<NG, 256, 0, stream>>>(h1b, wp1, al1, ar1, featb, el, er);
    gat_agg<1, 1, 0, 1><<<(NN * 64 + 255) / 256, 256, 0, stream>>>(
        esort, src, offs, featb, el, er, h1b, b1, outh, nullptr, atto);
}

// Round 18
// 530.303 us; speedup vs baseline: 1.2020x; 1.0023x over previous
//
#include <hip/hip_runtime.h>
#include <math.h>

#define NN 50000
#define EE 800000
#define NEG 0.2f
#define NG (NN / 16)   // 3125 node groups

using f32x4  = __attribute__((ext_vector_type(4))) float;
using bf16x8 = __attribute__((ext_vector_type(8))) short;

__device__ __forceinline__ float lrelu(float x){ return x > 0.f ? x : NEG*x; }

__device__ __forceinline__ unsigned short f2b(float f){
    unsigned int u = __float_as_uint(f);
    return (unsigned short)((u + 0x7FFFu + ((u >> 16) & 1u)) >> 16);  // RNE
}
__device__ __forceinline__ float b2f(unsigned short h){
    return __uint_as_float(((unsigned int)h) << 16);
}
__device__ __forceinline__ void gld_lds16(const void* g, void* l){
    __builtin_amdgcn_global_load_lds(
        (const __attribute__((address_space(1))) unsigned int*)g,
        (__attribute__((address_space(3))) unsigned int*)l, 16, 0, 0);
}
__device__ __forceinline__ unsigned int cvtpk(float lo, float hi){
    unsigned int r;
    asm volatile("v_cvt_pk_bf16_f32 %0, %1, %2" : "=v"(r) : "v"(lo), "v"(hi));
    return r;
}

// ---------------------------------------------------------------------------
// Combined weight packer (1 dispatch). Fragment-order bf16.
// ---------------------------------------------------------------------------
__device__ __forceinline__ void pw_fusion_body(
    const float* __restrict__ W, unsigned short* __restrict__ out, int K, int u)
{
    int l = u & 63, chunk = (u >> 6) & 15, kc = u >> 10;
    int ct = chunk >> 2, r = chunk & 3;
    int c = ct * 16 + (l & 15);
    int kb = kc * 32 + (l >> 4) * 8;
    bf16x8 v;
#pragma unroll
    for (int j = 0; j < 8; ++j)
        v[j] = (short)f2b(W[((size_t)r * K + kb + j) * 64 + c]);
    *(bf16x8*)(out + (size_t)u * 8) = v;
}

__device__ __forceinline__ void pw_gemm_body(
    const float* __restrict__ W, unsigned short* __restrict__ out,
    int C, int PERM, int u)
{
    int NCH = C / 16;
    int l = u & 63, ch = (u >> 6) % NCH, kc = u / (64 * NCH);
    int c = ch * 16 + (l & 15);
    int kb = kc * 32 + (l >> 4) * 8;
    bf16x8 v;
#pragma unroll
    for (int j = 0; j < 8; ++j) {
        int k = kb + j;
        int ko = PERM ? ((k & 3) * 64 + (k >> 2)) : k;
        v[j] = (short)f2b(W[(size_t)ko * C + c]);
    }
    *(bf16x8*)(out + (size_t)u * 8) = v;
}

__global__ __launch_bounds__(256) void pack_all_w(
    const float* __restrict__ Wc, const float* __restrict__ Wt, const float* __restrict__ Wr,
    const float* __restrict__ W0, const float* __restrict__ W1,
    unsigned short* __restrict__ wpc, unsigned short* __restrict__ wpt,
    unsigned short* __restrict__ wpr, unsigned short* __restrict__ wp0,
    unsigned short* __restrict__ wp1)
{
    int b = blockIdx.x, t = threadIdx.x;
    if (b < 16)        pw_fusion_body(Wc, wpc, 129, b * 256 + t);
    else if (b < 80)   pw_fusion_body(Wt, wpt, 513, (b - 16) * 256 + t);
    else if (b < 144)  pw_fusion_body(Wr, wpr, 513, (b - 80) * 256 + t);
    else if (b < 152)  pw_gemm_body(W0, wp0, 256, 0, (b - 144) * 256 + t);
    else               pw_gemm_body(W1, wp1, 256, 1, (b - 152) * 256 + t);
}

// ---------------------------------------------------------------------------
// Fusion, rank-split + direct f32 LDS staging via WIDTH-16 global_load_lds
// with both-sides XOR swizzle (rule #21):
//   - chunk = 16 rows x 32 dwords (2048B), staged by 2 gld_lds16 (linear dest)
//   - source pre-swizzled: lane l, instr i reads row i*8+(l>>3), 16B-slot
//     (l&7)^((l>>3)&7) of that row's 128B k-window  (same-line permutation)
//   - reads apply slot ^= (row&7)  ->  2-way bank access (free)
// A-frag: 2x f32x4 LDS read + v_cvt_pk_bf16_f32 x4. B-frags global (L2-hot).
// ---------------------------------------------------------------------------
__global__ __launch_bounds__(256) void fusion_mfma(
    const float* __restrict__ hc, const float* __restrict__ ht, const float* __restrict__ hr,
    const unsigned short* __restrict__ wpc, const unsigned short* __restrict__ wpt,
    const unsigned short* __restrict__ wpr,
    const float* __restrict__ Wc, const float* __restrict__ Wt, const float* __restrict__ Wr,
    const float* __restrict__ fw, const float* __restrict__ fb,
    unsigned short* __restrict__ h0b)
{
    __shared__ __align__(16) float lds[18 * 512];    // 18 chunks x 2048B = 36,864B
    float* ldsx = lds;                               // aliased exchange (16KB)
    const int w = threadIdx.x >> 6, l = threadIdx.x & 63;
    const int G = blockIdx.x, nb = G * 16;
    const int c_lo = l & 15;

    // staging source geometry (same for all chunks; i adds 8 rows)
    const int r0 = l >> 3;                       // row within 8-row half
    const int xs = ((l & 7) ^ (r0 & 7)) * 4;     // pre-swizzled dword offset

    // A-frag read geometry
    const int arow = l & 15;
    const int asl0 = ((l >> 4) * 2) ^ (arow & 7);
    const int asl1 = ((l >> 4) * 2 + 1) ^ (arow & 7);

    auto aread = [&](int slot) -> bf16x8 {
        const float* base = lds + slot * 512 + arow * 32;
        f32x4 a = *(const f32x4*)(base + asl0 * 4);
        f32x4 b = *(const f32x4*)(base + asl1 * 4);
        union { unsigned int wd[4]; bf16x8 v; } u;
        u.wd[0] = cvtpk(a[0], a[1]);
        u.wd[1] = cvtpk(a[2], a[3]);
        u.wd[2] = cvtpk(b[0], b[1]);
        u.wd[3] = cvtpk(b[2], b[3]);
        return u.v;
    };

    auto stage_half = [&](int half) {
        for (int cid = w; cid < 18; cid += 4) {
            int gcid = half * 18 + cid;
            const float* F; int K, kc;
            if (gcid < 4)       { F = hc; K = 129; kc = gcid; }
            else if (gcid < 20) { F = ht; K = 513; kc = gcid - 4; }
            else                { F = hr; K = 513; kc = gcid - 20; }
#pragma unroll
            for (int i = 0; i < 2; ++i) {
                const float* g = F + (size_t)(nb + i * 8 + r0) * K + kc * 32 + xs;
                gld_lds16(g, lds + cid * 512 + i * 256);
            }
        }
    };

    f32x4 prod[4], accT[4], acc[4];

    // ---- half 0: hc chunks g0-3, ht kc0-13 (slots 4-17) ----
    stage_half(0);
    __syncthreads();

#pragma unroll
    for (int ct = 0; ct < 4; ++ct) {
        float wi = Wc[((size_t)w * 129 + 128) * 64 + ct * 16 + c_lo];
        prod[ct] = f32x4{wi, wi, wi, wi};
    }
#pragma unroll
    for (int kc = 0; kc < 4; ++kc) {
        bf16x8 af = aread(kc);
        const unsigned short* wk = wpc + (size_t)kc * 8192 + w * 512 + l * 8;
#pragma unroll
        for (int ct = 0; ct < 4; ++ct) {
            bf16x8 bf = *(const bf16x8*)(wk + ct * 2048);
            prod[ct] = __builtin_amdgcn_mfma_f32_16x16x32_bf16(af, bf, prod[ct], 0, 0, 0);
        }
    }
#pragma unroll
    for (int ct = 0; ct < 4; ++ct) {
        float wi = Wt[((size_t)w * 513 + 512) * 64 + ct * 16 + c_lo];
        accT[ct] = f32x4{wi, wi, wi, wi};
    }
#pragma unroll
    for (int kc = 0; kc < 14; ++kc) {
        bf16x8 af = aread(4 + kc);
        const unsigned short* wk = wpt + (size_t)kc * 8192 + w * 512 + l * 8;
#pragma unroll
        for (int ct = 0; ct < 4; ++ct) {
            bf16x8 bf = *(const bf16x8*)(wk + ct * 2048);
            accT[ct] = __builtin_amdgcn_mfma_f32_16x16x32_bf16(af, bf, accT[ct], 0, 0, 0);
        }
    }

    // ---- half 1: ht kc14-15 (slots 0-1), hr kc0-15 (slots 2-17) ----
    __syncthreads();
    stage_half(1);
    __syncthreads();

#pragma unroll
    for (int kc = 14; kc < 16; ++kc) {
        bf16x8 af = aread(kc - 14);
        const unsigned short* wk = wpt + (size_t)kc * 8192 + w * 512 + l * 8;
#pragma unroll
        for (int ct = 0; ct < 4; ++ct) {
            bf16x8 bf = *(const bf16x8*)(wk + ct * 2048);
            accT[ct] = __builtin_amdgcn_mfma_f32_16x16x32_bf16(af, bf, accT[ct], 0, 0, 0);
        }
    }
#pragma unroll
    for (int ct = 0; ct < 4; ++ct) {
        prod[ct] *= accT[ct];
        float wi = Wr[((size_t)w * 513 + 512) * 64 + ct * 16 + c_lo];
        acc[ct] = f32x4{wi, wi, wi, wi};
    }
#pragma unroll
    for (int kc = 0; kc < 16; ++kc) {
        bf16x8 af = aread(2 + kc);
        const unsigned short* wk = wpr + (size_t)kc * 8192 + w * 512 + l * 8;
#pragma unroll
        for (int ct = 0; ct < 4; ++ct) {
            bf16x8 bf = *(const bf16x8*)(wk + ct * 2048);
            acc[ct] = __builtin_amdgcn_mfma_f32_16x16x32_bf16(af, bf, acc[ct], 0, 0, 0);
        }
    }
    const float fww = fw[w];
#pragma unroll
    for (int ct = 0; ct < 4; ++ct) prod[ct] = prod[ct] * acc[ct] * fww;

    // ---- rank exchange (aliased LDS) + epilogue ----
    __syncthreads();
#pragma unroll
    for (int ct = 0; ct < 4; ++ct)
        *(f32x4*)&ldsx[((w * 4 + ct) * 64 + l) * 4] = prod[ct];
    __syncthreads();

    f32x4 s = *(const f32x4*)&ldsx[((0 * 4 + w) * 64 + l) * 4];
#pragma unroll
    for (int r = 1; r < 4; ++r)
        s += *(const f32x4*)&ldsx[((r * 4 + w) * 64 + l) * 4];

    const int c = w * 16 + c_lo;
    const float fbc = fb[c];
#pragma unroll
    for (int q = 0; q < 4; ++q) {
        int n = nb + (l >> 4) * 4 + q;
        float v = s[q] + fbc;
        v = v > 0.f ? v : expm1f(v);
        h0b[(size_t)n * 64 + c] = f2b(v);
    }
}

// ---------------------------------------------------------------------------
// feat GEMM with FUSED el/er epilogue. HEAD-MINOR output featb[n][d*4+h].
// ---------------------------------------------------------------------------
template<int K>
__global__ __launch_bounds__(256) void gemm_reg(
    const unsigned short* __restrict__ Ab, const unsigned short* __restrict__ wp,
    const float* __restrict__ al, const float* __restrict__ ar,
    unsigned short* __restrict__ featb,
    float* __restrict__ el, float* __restrict__ er)
{
    constexpr int NKC = K / 32;
    const int w = threadIdx.x >> 6, l = threadIdx.x & 63;
    const int nb = blockIdx.x * 16;

    f32x4 acc[4];
#pragma unroll
    for (int i = 0; i < 4; ++i) acc[i] = f32x4{0.f, 0.f, 0.f, 0.f};

    const unsigned short* abase = Ab + (size_t)(nb + (l & 15)) * K + (l >> 4) * 8;
    bf16x8 afs[NKC];
#pragma unroll
    for (int kc = 0; kc < NKC; ++kc)
        afs[kc] = *(const bf16x8*)(abase + kc * 32);

    bf16x8 bcur[4];
    {
        const unsigned short* wk = wp + (size_t)(0 * 16 + w * 4) * 512 + l * 8;
#pragma unroll
        for (int i = 0; i < 4; ++i) bcur[i] = *(const bf16x8*)(wk + i * 512);
    }
#pragma unroll
    for (int kc = 0; kc < NKC; ++kc) {
        bf16x8 bnxt[4];
        if (kc + 1 < NKC) {
            const unsigned short* wk = wp + ((size_t)(kc + 1) * 16 + w * 4) * 512 + l * 8;
#pragma unroll
            for (int i = 0; i < 4; ++i) bnxt[i] = *(const bf16x8*)(wk + i * 512);
        }
#pragma unroll
        for (int i = 0; i < 4; ++i)
            acc[i] = __builtin_amdgcn_mfma_f32_16x16x32_bf16(afs[kc], bcur[i], acc[i], 0, 0, 0);
        if (kc + 1 < NKC) {
#pragma unroll
            for (int i = 0; i < 4; ++i) bcur[i] = bnxt[i];
        }
    }

#pragma unroll
    for (int i = 0; i < 4; ++i) {
        int c = (w * 4 + i) * 16 + (l & 15);
        int dm = (c & 63) * 4 + (c >> 6);
#pragma unroll
        for (int q = 0; q < 4; ++q) {
            int n = nb + (l >> 4) * 4 + q;
            featb[(size_t)n * 256 + dm] = f2b(acc[i][q]);
        }
    }

    float pel[4] = {0.f, 0.f, 0.f, 0.f};
    float per_[4] = {0.f, 0.f, 0.f, 0.f};
#pragma unroll
    for (int i = 0; i < 4; ++i) {
        int d = i * 16 + (l & 15);
        float av = al[w * 64 + d];
        float rv = ar[w * 64 + d];
#pragma unroll
        for (int q = 0; q < 4; ++q) {
            pel[q] += acc[i][q] * av;
            per_[q] += acc[i][q] * rv;
        }
    }
#pragma unroll
    for (int off = 1; off <= 8; off <<= 1) {
#pragma unroll
        for (int q = 0; q < 4; ++q) {
            pel[q] += __shfl_xor(pel[q], off);
            per_[q] += __shfl_xor(per_[q], off);
        }
    }
    int qsel = l & 15;
    if (qsel < 4) {
        float ev = qsel == 0 ? pel[0] : qsel == 1 ? pel[1] : qsel == 2 ? pel[2] : pel[3];
        float rv = qsel == 0 ? per_[0] : qsel == 1 ? per_[1] : qsel == 2 ? per_[2] : per_[3];
        int n = nb + (l >> 4) * 4 + qsel;
        el[(size_t)n * 4 + w] = ev;
        er[(size_t)n * 4 + w] = rv;
    }
}

// ---------------------------------------------------------------------------
// CSR build (scan re-zeroes cnt for scatter)
// ---------------------------------------------------------------------------
__global__ void hist_kernel(const int* __restrict__ dst, int* __restrict__ cnt)
{
    int e = blockIdx.x * blockDim.x + threadIdx.x;
    if (e < EE) atomicAdd(&cnt[dst[e]], 1);
}

__global__ __launch_bounds__(1024) void scan_kernel(int* __restrict__ cnt, int* __restrict__ offs)
{
    __shared__ int tmp[1024];
    const int t = threadIdx.x;
    const int C = (NN + 1023) / 1024;
    int lo = t * C, hi = min(lo + C, NN);
    int s = 0;
    for (int i = lo; i < hi; ++i) s += cnt[i];
    tmp[t] = s;
    __syncthreads();
    for (int off = 1; off < 1024; off <<= 1) {
        int v = (t >= off) ? tmp[t - off] : 0;
        __syncthreads();
        tmp[t] += v;
        __syncthreads();
    }
    int run = (t == 0) ? 0 : tmp[t - 1];
    for (int i = lo; i < hi; ++i) { offs[i] = run; run += cnt[i]; cnt[i] = 0; }
    if (t == 1023) offs[NN] = tmp[1023];
}

__global__ void scatter_kernel(const int* __restrict__ dst, const int* __restrict__ offs,
                               int* __restrict__ cur, int* __restrict__ esort)
{
    int e = blockIdx.x * blockDim.x + threadIdx.x;
    if (e < EE) {
        int d = dst[e];
        int p = offs[d] + atomicAdd(&cur[d], 1);
        esort[p] = e;
    }
}

// ---------------------------------------------------------------------------
// gat_agg, register-cached softmax (deg<=64 fast path; lane owns one edge).
// ---------------------------------------------------------------------------
template <int RESID, int WATT, int WB16, int WF32>
__global__ __launch_bounds__(256) void gat_agg(
    const int* __restrict__ esort, const int* __restrict__ src, const int* __restrict__ offs,
    const unsigned short* __restrict__ featb,
    const float* __restrict__ el, const float* __restrict__ er,
    const unsigned short* __restrict__ residb, const float* __restrict__ bias,
    float* __restrict__ out, unsigned short* __restrict__ outb,
    float4* __restrict__ att)
{
    int n = (int)((blockIdx.x * (size_t)blockDim.x + threadIdx.x) >> 6);
    int lane = threadIdx.x & 63;
    if (n >= NN) return;
    const int s0 = offs[n], s1 = offs[n + 1], deg = s1 - s0;
    const float4 r4 = *(const float4*)(er + (size_t)n * 4);

    float a0 = 0.f, a1 = 0.f, a2 = 0.f, a3 = 0.f;
    float i0, i1, i2, i3;

    if (deg <= 64) {
        int p = s0 + lane;
        bool valid = p < s1;
        int e = valid ? esort[p] : 0;
        int sv = valid ? src[e] : 0;
        float v0 = -1e30f, v1 = -1e30f, v2 = -1e30f, v3 = -1e30f;
        if (valid) {
            float4 l4 = *(const float4*)(el + (size_t)sv * 4);
            v0 = lrelu(l4.x + r4.x); v1 = lrelu(l4.y + r4.y);
            v2 = lrelu(l4.z + r4.z); v3 = lrelu(l4.w + r4.w);
        }
        float m0 = v0, m1 = v1, m2 = v2, m3 = v3;
#pragma unroll
        for (int off = 32; off; off >>= 1) {
            m0 = fmaxf(m0, __shfl_xor(m0, off));
            m1 = fmaxf(m1, __shfl_xor(m1, off));
            m2 = fmaxf(m2, __shfl_xor(m2, off));
            m3 = fmaxf(m3, __shfl_xor(m3, off));
        }
        float e0 = valid ? expf(v0 - m0) : 0.f;
        float e1 = valid ? expf(v1 - m1) : 0.f;
        float e2 = valid ? expf(v2 - m2) : 0.f;
        float e3 = valid ? expf(v3 - m3) : 0.f;
        float z0 = e0, z1 = e1, z2 = e2, z3 = e3;
#pragma unroll
        for (int off = 32; off; off >>= 1) {
            z0 += __shfl_xor(z0, off);
            z1 += __shfl_xor(z1, off);
            z2 += __shfl_xor(z2, off);
            z3 += __shfl_xor(z3, off);
        }
        float j0 = z0 > 0.f ? 1.f / z0 : 0.f;
        float j1 = z1 > 0.f ? 1.f / z1 : 0.f;
        float j2 = z2 > 0.f ? 1.f / z2 : 0.f;
        float j3 = z3 > 0.f ? 1.f / z3 : 0.f;
        e0 *= j0; e1 *= j1; e2 *= j2; e3 *= j3;
        if (WATT && valid)
            att[e] = make_float4(e0, e1, e2, e3);
        for (int jj = 0; jj < deg; ++jj) {
            float w0 = __shfl(e0, jj), w1 = __shfl(e1, jj);
            float w2 = __shfl(e2, jj), w3 = __shfl(e3, jj);
            int s = __shfl(sv, jj);
            ushort4 f = *(const ushort4*)(featb + (size_t)s * 256 + lane * 4);
            a0 += w0 * b2f(f.x);
            a1 += w1 * b2f(f.y);
            a2 += w2 * b2f(f.z);
            a3 += w3 * b2f(f.w);
        }
        i0 = i1 = i2 = i3 = 1.f;
    } else {
        float m0 = -1e30f, m1 = -1e30f, m2 = -1e30f, m3 = -1e30f;
        for (int p = s0 + lane; p < s1; p += 64) {
            int s = src[esort[p]];
            float4 l4 = *(const float4*)(el + (size_t)s * 4);
            m0 = fmaxf(m0, lrelu(l4.x + r4.x));
            m1 = fmaxf(m1, lrelu(l4.y + r4.y));
            m2 = fmaxf(m2, lrelu(l4.z + r4.z));
            m3 = fmaxf(m3, lrelu(l4.w + r4.w));
        }
#pragma unroll
        for (int off = 32; off; off >>= 1) {
            m0 = fmaxf(m0, __shfl_xor(m0, off));
            m1 = fmaxf(m1, __shfl_xor(m1, off));
            m2 = fmaxf(m2, __shfl_xor(m2, off));
            m3 = fmaxf(m3, __shfl_xor(m3, off));
        }
        float z0 = 0.f, z1 = 0.f, z2 = 0.f, z3 = 0.f;
        for (int p = s0 + lane; p < s1; p += 64) {
            int s = src[esort[p]];
            float4 l4 = *(const float4*)(el + (size_t)s * 4);
            z0 += expf(lrelu(l4.x + r4.x) - m0);
            z1 += expf(lrelu(l4.y + r4.y) - m1);
            z2 += expf(lrelu(l4.z + r4.z) - m2);
            z3 += expf(lrelu(l4.w + r4.w) - m3);
        }
#pragma unroll
        for (int off = 32; off; off >>= 1) {
            z0 += __shfl_xor(z0, off);
            z1 += __shfl_xor(z1, off);
            z2 += __shfl_xor(z2, off);
            z3 += __shfl_xor(z3, off);
        }
        i0 = z0 > 0.f ? 1.f / z0 : 0.f;
        i1 = z1 > 0.f ? 1.f / z1 : 0.f;
        i2 = z2 > 0.f ? 1.f / z2 : 0.f;
        i3 = z3 > 0.f ? 1.f / z3 : 0.f;
        for (int p = s0; p < s1; ++p) {
            int e = esort[p];
            int s = src[e];
            float4 l4 = *(const float4*)(el + (size_t)s * 4);
            float w0 = expf(lrelu(l4.x + r4.x) - m0);
            float w1 = expf(lrelu(l4.y + r4.y) - m1);
            float w2 = expf(lrelu(l4.z + r4.z) - m2);
            float w3 = expf(lrelu(l4.w + r4.w) - m3);
            ushort4 f = *(const ushort4*)(featb + (size_t)s * 256 + lane * 4);
            a0 += w0 * b2f(f.x);
            a1 += w1 * b2f(f.y);
            a2 += w2 * b2f(f.z);
            a3 += w3 * b2f(f.w);
            if (WATT && lane == 0)
                att[e] = make_float4(w0 * i0, w1 * i1, w2 * i2, w3 * i3);
        }
    }

    float o0 = a0 * i0 + bias[lane];
    float o1 = a1 * i1 + bias[64 + lane];
    float o2 = a2 * i2 + bias[128 + lane];
    float o3 = a3 * i3 + bias[192 + lane];
    if (RESID) {
        ushort4 rp = *(const ushort4*)(residb + (size_t)n * 256 + lane * 4);
        o0 += b2f(rp.x); o1 += b2f(rp.y); o2 += b2f(rp.z); o3 += b2f(rp.w);
    }
    if (WF32) {
        float* op = out + (size_t)n * 256;
        op[lane] = o0;
        op[64 + lane] = o1;
        op[128 + lane] = o2;
        op[192 + lane] = o3;
    }
    if (WB16) {
        ushort4 ob;
        ob.x = f2b(o0); ob.y = f2b(o1); ob.z = f2b(o2); ob.w = f2b(o3);
        *(ushort4*)(outb + (size_t)n * 256 + lane * 4) = ob;
    }
}

// ---------------------------------------------------------------------------
extern "C" void kernel_launch(void* const* d_in, const int* in_sizes, int n_in,
                              void* d_out, int out_size, void* d_ws, size_t ws_size,
                              hipStream_t stream)
{
    const int*   src = (const int*)d_in[0];
    const int*   dst = (const int*)d_in[1];
    const float* hc  = (const float*)d_in[2];
    const float* ht  = (const float*)d_in[3];
    const float* hr  = (const float*)d_in[4];
    const float* Wc  = (const float*)d_in[5];
    const float* Wt  = (const float*)d_in[6];
    const float* Wr  = (const float*)d_in[7];
    const float* fw  = (const float*)d_in[8];
    const float* fb  = (const float*)d_in[9];
    const float* W0  = (const float*)d_in[10];
    const float* al0 = (const float*)d_in[11];
    const float* ar0 = (const float*)d_in[12];
    const float* b0  = (const float*)d_in[13];
    const float* W1  = (const float*)d_in[14];
    const float* al1 = (const float*)d_in[15];
    const float* ar1 = (const float*)d_in[16];
    const float* b1  = (const float*)d_in[17];

    // workspace layout (bytes); proven ws_size >= 63,553,792
    char* ws = (char*)d_ws;
    unsigned short* h0b   = (unsigned short*)(ws);               // N*64  bf16 :  6,400,000
    unsigned short* h1b   = (unsigned short*)(ws + 6400000);     // N*256 bf16 : 25,600,000 (head-minor)
    unsigned short* featb = (unsigned short*)(ws + 32000000);    // N*256 bf16 : 25,600,000 (head-minor)
    float* el    = (float*)(ws + 57600000);                      //    800,000
    float* er    = (float*)(ws + 58400000);                      //    800,000
    int*   cnt   = (int*)  (ws + 59200000);                      //    200,000
    int*   offs  = (int*)  (ws + 59400000);                      //    200,064 (padded)
    int*   esort = (int*)  (ws + 59600128);                      //  3,200,000
    unsigned short* wpc = (unsigned short*)(ws + 62800128);      //  4*16KB =  65,536
    unsigned short* wpt = (unsigned short*)(ws + 62865664);      // 16*16KB = 262,144
    unsigned short* wpr = (unsigned short*)(ws + 63127808);      // 16*16KB = 262,144
    unsigned short* wp0 = (unsigned short*)(ws + 63389952);      //  2*16KB =  32,768
    unsigned short* wp1 = (unsigned short*)(ws + 63422720);      //  8*16KB = 131,072
    if (ws_size < 63553792ull) return;                           // end of layout

    float* outh = (float*)d_out;                       // N*256 final h
    float4* atto = (float4*)(outh + (size_t)NN * 256); // E*4 att region

    // weight packing (single dispatch)
    pack_all_w<<<184, 256, 0, stream>>>(Wc, Wt, Wr, W0, W1, wpc, wpt, wpr, wp0, wp1);

    // trilinear fusion (rank-split, width-16 swizzled f32 staging)
    fusion_mfma<<<NG, 256, 0, stream>>>(hc, ht, hr, wpc, wpt, wpr,
                                        Wc, Wt, Wr, fw, fb, h0b);

    // CSR by dst (scan re-zeroes cnt for scatter)
    hipMemsetAsync(cnt, 0, NN * sizeof(int), stream);
    hist_kernel<<<(EE + 255) / 256, 256, 0, stream>>>(dst, cnt);
    scan_kernel<<<1, 1024, 0, stream>>>(cnt, offs);
    scatter_kernel<<<(EE + 255) / 256, 256, 0, stream>>>(dst, offs, cnt, esort);

    // GAT layer 0: feat + el/er fused; softmax+agg in-register; bf16 h1b out
    gemm_reg<64><<<NG, 256, 0, stream>>>(h0b, wp0, al0, ar0, featb, el, er);
    gat_agg<0, 0, 1, 0><<<(NN * 64 + 255) / 256, 256, 0, stream>>>(
        esort, src, offs, featb, el, er, nullptr, b0, nullptr, h1b, nullptr);

    // GAT layer 1: residual from bf16 h1b; f32 out + attention (per-lane)
    gemm_reg<256><<<NG, 256, 0, stream>>>(h1b, wp1, al1, ar1, featb, el, er);
    gat_agg<1, 1, 0, 1><<<(NN * 64 + 255) / 256, 256, 0, stream>>>(
        esort, src, offs, featb, el, er, h1b, b1, outh, nullptr, atto);
}